// Round 7
// baseline (1026.712 us; speedup 1.0000x reference)
//
#include <hip/hip_runtime.h>
#include <cstdint>
#include <cstddef>

#define NN 100000
#define NE 1000000
#define FIN 128
#define HD 256
#define NG 64
#define BNEPS 1e-5f

typedef unsigned short ushort_t;
typedef __attribute__((ext_vector_type(8))) short bf16x8;
typedef __attribute__((ext_vector_type(4))) float f32x4;

// ---------- bf16<->f32 helpers (storage is raw bf16 bits in ushort) ----------

__device__ inline float b2f(unsigned short u) {
    union { float f; unsigned int i; } x; x.i = ((unsigned int)u) << 16; return x.f;
}
__device__ inline unsigned short f2b(float f) {
    union { float f; unsigned int i; } x; x.f = f;
    unsigned int r = x.i + 0x7FFFu + ((x.i >> 16) & 1u);
    return (unsigned short)(r >> 16);
}
__device__ inline float  ld1(const unsigned short* p) { return b2f(*p); }
__device__ inline float4 ld4v(const unsigned short* p) {
    ushort4 u = *(const ushort4*)p;
    return make_float4(b2f(u.x), b2f(u.y), b2f(u.z), b2f(u.w));
}
__device__ inline float2 ld2v(const unsigned short* p) {
    ushort2 u = *(const ushort2*)p;
    return make_float2(b2f(u.x), b2f(u.y));
}
__device__ inline void st4v(unsigned short* p, float4 v) {
    ushort4 u; u.x = f2b(v.x); u.y = f2b(v.y); u.z = f2b(v.z); u.w = f2b(v.w);
    *(ushort4*)p = u;
}
__device__ inline void st2v(unsigned short* p, float2 v) {
    ushort2 u; u.x = f2b(v.x); u.y = f2b(v.y);
    *(ushort2*)p = u;
}

// ---------------- graph preprocessing ----------------

__global__ __launch_bounds__(256) void count_deg_k(const int* __restrict__ dst, int* __restrict__ cnt) {
    int e = blockIdx.x * 256 + threadIdx.x;
    if (e < NE) atomicAdd(&cnt[dst[e]], 1);
}

__global__ __launch_bounds__(256) void node_prep_k(const int* __restrict__ cnt,
                                                   float* __restrict__ dis, float* __restrict__ selfw) {
    int i = blockIdx.x * 256 + threadIdx.x;
    if (i < NN) {
        float d = (float)cnt[i] + 1.0f;
        dis[i] = rsqrtf(d);
        selfw[i] = 1.0f / d;
    }
}

__global__ __launch_bounds__(1024) void scan_reduce_k(const int* __restrict__ cnt, int* __restrict__ partials) {
    __shared__ int sh[1024];
    int i = blockIdx.x * 1024 + threadIdx.x;
    sh[threadIdx.x] = (i < NN) ? cnt[i] : 0;
    __syncthreads();
    for (int off = 512; off > 0; off >>= 1) {
        if (threadIdx.x < off) sh[threadIdx.x] += sh[threadIdx.x + off];
        __syncthreads();
    }
    if (threadIdx.x == 0) partials[blockIdx.x] = sh[0];
}

__global__ void scan_partials_k(int* partials, int nb) {
    if (threadIdx.x == 0 && blockIdx.x == 0) {
        int run = 0;
        for (int b = 0; b < nb; b++) { int v = partials[b]; partials[b] = run; run += v; }
    }
}

__global__ __launch_bounds__(1024) void scan_write_k(const int* __restrict__ cnt,
                                                     const int* __restrict__ partials,
                                                     int* __restrict__ rowptr) {
    __shared__ int sh[1024];
    int i = blockIdx.x * 1024 + threadIdx.x;
    int v = (i < NN) ? cnt[i] : 0;
    sh[threadIdx.x] = v;
    __syncthreads();
    for (int off = 1; off < 1024; off <<= 1) {
        int t = (threadIdx.x >= off) ? sh[threadIdx.x - off] : 0;
        __syncthreads();
        sh[threadIdx.x] += t;
        __syncthreads();
    }
    if (i < NN) rowptr[i] = partials[blockIdx.x] + sh[threadIdx.x] - v;
    if (i == NN - 1) rowptr[NN] = partials[blockIdx.x] + sh[threadIdx.x];
}

// CSR packed as int2 {src, weight_bits}: one 8B load per edge in the SpMM.
__global__ __launch_bounds__(256) void fill_csr_k(const int* __restrict__ src, const int* __restrict__ dst,
                                                  const int* __restrict__ rowptr, int* __restrict__ cursor,
                                                  const float* __restrict__ dis,
                                                  int2* __restrict__ csr) {
    int e = blockIdx.x * 256 + threadIdx.x;
    if (e < NE) {
        int d = dst[e], s = src[e];
        int pos = rowptr[d] + atomicAdd(&cursor[d], 1);
        float w = dis[s] * dis[d];
        csr[pos] = make_int2(s, __float_as_int(w));
    }
}

// ---- x (fp32 [N,128]) -> bf16 ----
__global__ __launch_bounds__(256) void x2b_k(const float* __restrict__ x, unsigned short* __restrict__ xb) {
    int i = blockIdx.x * 256 + threadIdx.x;
    if (i < NN * FIN / 4) {
        float4 v = *reinterpret_cast<const float4*>(x + (size_t)i * 4);
        ushort4 u; u.x = f2b(v.x); u.y = f2b(v.y); u.z = f2b(v.z); u.w = f2b(v.w);
        *reinterpret_cast<ushort4*>(xb + (size_t)i * 4) = u;
    }
}

// ---- weight prep, all 5 in one launch: W[K][256] fp32 -> Bt[256][K] bf16 ----
__global__ __launch_bounds__(256) void wt_all_k(const float* __restrict__ W1, const float* __restrict__ P1,
                                                const float* __restrict__ W2, const float* __restrict__ W3,
                                                const float* __restrict__ W4,
                                                unsigned short* __restrict__ w1t, unsigned short* __restrict__ p1t,
                                                unsigned short* __restrict__ w2t, unsigned short* __restrict__ w3t,
                                                unsigned short* __restrict__ w4t) {
    int b = blockIdx.x;
    const float* W; unsigned short* Bt; int K; int base;
    if (b < 128)      { W = W1; Bt = w1t; K = 128; base = b; }
    else if (b < 256) { W = P1; Bt = p1t; K = 128; base = b - 128; }
    else if (b < 512) { W = W2; Bt = w2t; K = 256; base = b - 256; }
    else if (b < 768) { W = W3; Bt = w3t; K = 256; base = b - 512; }
    else              { W = W4; Bt = w4t; K = 256; base = b - 768; }
    int i = base * 256 + threadIdx.x;
    if (i < K * 256) {
        int k = i >> 8, n = i & 255;
        Bt[n * K + k] = f2b(W[k * 256 + n]);
    }
}

// ---------------- SpMM: z[i,:] = selfw[i]*h[i,:] + sum_e w_e * h[src_e,:] ----------------

template<int COLS>
__global__ __launch_bounds__(256) void spmm_k(const unsigned short* __restrict__ h,
                                              const int* __restrict__ rowptr,
                                              const int2* __restrict__ csr,
                                              const float* __restrict__ selfw,
                                              unsigned short* __restrict__ z) {
    const int lane = threadIdx.x & 63;
    const int row = blockIdx.x * 4 + (threadIdx.x >> 6);
    if (row >= NN) return;
    if constexpr (COLS == 256) {
        float4 a = ld4v(h + (size_t)row * COLS + lane * 4);
        float sw = selfw[row];
        float4 acc = make_float4(a.x * sw, a.y * sw, a.z * sw, a.w * sw);
        int e = rowptr[row];
        const int e1 = rowptr[row + 1];
        for (; e + 4 <= e1; e += 4) {
            int2 c0 = csr[e], c1 = csr[e + 1], c2 = csr[e + 2], c3 = csr[e + 3];
            float4 h0 = ld4v(h + (size_t)c0.x * COLS + lane * 4);
            float4 h1 = ld4v(h + (size_t)c1.x * COLS + lane * 4);
            float4 h2 = ld4v(h + (size_t)c2.x * COLS + lane * 4);
            float4 h3 = ld4v(h + (size_t)c3.x * COLS + lane * 4);
            float w0 = __int_as_float(c0.y), w1 = __int_as_float(c1.y);
            float w2 = __int_as_float(c2.y), w3 = __int_as_float(c3.y);
            acc.x += w0 * h0.x; acc.y += w0 * h0.y; acc.z += w0 * h0.z; acc.w += w0 * h0.w;
            acc.x += w1 * h1.x; acc.y += w1 * h1.y; acc.z += w1 * h1.z; acc.w += w1 * h1.w;
            acc.x += w2 * h2.x; acc.y += w2 * h2.y; acc.z += w2 * h2.z; acc.w += w2 * h2.w;
            acc.x += w3 * h3.x; acc.y += w3 * h3.y; acc.z += w3 * h3.z; acc.w += w3 * h3.w;
        }
        for (; e < e1; e++) {
            int2 c = csr[e];
            float w = __int_as_float(c.y);
            float4 hv = ld4v(h + (size_t)c.x * COLS + lane * 4);
            acc.x += w * hv.x; acc.y += w * hv.y; acc.z += w * hv.z; acc.w += w * hv.w;
        }
        st4v(z + (size_t)row * COLS + lane * 4, acc);
    } else {
        float2 a = ld2v(h + (size_t)row * COLS + lane * 2);
        float sw = selfw[row];
        float2 acc = make_float2(a.x * sw, a.y * sw);
        int e = rowptr[row];
        const int e1 = rowptr[row + 1];
        for (; e + 4 <= e1; e += 4) {
            int2 c0 = csr[e], c1 = csr[e + 1], c2 = csr[e + 2], c3 = csr[e + 3];
            float2 h0 = ld2v(h + (size_t)c0.x * COLS + lane * 2);
            float2 h1 = ld2v(h + (size_t)c1.x * COLS + lane * 2);
            float2 h2 = ld2v(h + (size_t)c2.x * COLS + lane * 2);
            float2 h3 = ld2v(h + (size_t)c3.x * COLS + lane * 2);
            float w0 = __int_as_float(c0.y), w1 = __int_as_float(c1.y);
            float w2 = __int_as_float(c2.y), w3 = __int_as_float(c3.y);
            acc.x += w0 * h0.x; acc.y += w0 * h0.y;
            acc.x += w1 * h1.x; acc.y += w1 * h1.y;
            acc.x += w2 * h2.x; acc.y += w2 * h2.y;
            acc.x += w3 * h3.x; acc.y += w3 * h3.y;
        }
        for (; e < e1; e++) {
            int2 c = csr[e];
            float w = __int_as_float(c.y);
            float2 hv = ld2v(h + (size_t)c.x * COLS + lane * 2);
            acc.x += w * hv.x; acc.y += w * hv.y;
        }
        st2v(z + (size_t)row * COLS + lane * 2, acc);
    }
}

// ---------------- MFMA bf16 GEMM, m97-structure ----------------
// Tile 128(M) x 128(N), BK=64, 256 threads = 4 waves of 64x64. grid = (ceil(M/128), 2).
// global_load_lds staging (pre-swizzled global source, linear LDS dest);
// LDS round-trip epilogue -> fully coalesced 32B/thread stores.
// MODE 0: C = A@B + bias, fused per-column BN sums (s, s^2) -> global atomics
// MODE 1: C = relu(aggin*scale + shift) + A@B

template<int K, int MODE>
__global__ __launch_bounds__(256) void mgemm_k(const unsigned short* __restrict__ A,
                                               const unsigned short* __restrict__ Bt,
                                               const float* __restrict__ bias,
                                               unsigned short* __restrict__ C,
                                               const float* __restrict__ scale,
                                               const float* __restrict__ shift,
                                               const unsigned short* __restrict__ aggin,
                                               float* __restrict__ sums, int M) {
    __shared__ char lds[32768];          // K-loop: A[16K]+B[16K]; epilogue: C-tile[32K]
    __shared__ float sstat[256];         // [s 128][q 128] (MODE 0)
    char* const Al = lds;
    char* const Bl = lds + 16384;
    const int tid  = threadIdx.x;
    const int lane = tid & 63;
    const int wid  = tid >> 6;           // 0..3
    const int wm = wid >> 1, wn = wid & 1;
    const int row0 = blockIdx.x * 128;
    const int col0 = blockIdx.y * 128;

    f32x4 acc[4][4];
#pragma unroll
    for (int i = 0; i < 4; i++)
#pragma unroll
        for (int j = 0; j < 4; j++) acc[i][j] = (f32x4){0.f, 0.f, 0.f, 0.f};

    if (MODE == 0) sstat[tid] = 0.f;

    for (int kt = 0; kt < K; kt += 64) {
        // stage A+B tiles: 4 passes x (1 KB A + 1 KB B) per wave, direct to LDS.
        // LDS dest linear; source pre-swizzled: LDS slot (r,seg) holds global seg^(r&7).
#pragma unroll
        for (int p = 0; p < 4; p++) {
            int base = p * 256 + wid * 64;            // wave-uniform
            int idx  = base + lane;
            int r = idx >> 3, seg = idx & 7;
            int sw = (seg ^ (r & 7)) << 3;            // element offset of swizzled 16B seg
            int ar = row0 + r; ar = ar < M ? ar : (M - 1);
            const unsigned short* ga = A + (size_t)ar * K + kt + sw;
            __builtin_amdgcn_global_load_lds((const void*)ga, (void*)(Al + base * 16), 16, 0, 0);
            const unsigned short* gb = Bt + (size_t)(col0 + r) * K + kt + sw;
            __builtin_amdgcn_global_load_lds((const void*)gb, (void*)(Bl + base * 16), 16, 0, 0);
        }
        __syncthreads();                              // drains vmcnt (compiler-inserted)

#pragma unroll
        for (int ks = 0; ks < 2; ks++) {
            bf16x8 af[4], bfr[4];
#pragma unroll
            for (int mf = 0; mf < 4; mf++) {
                int rr = wm * 64 + mf * 16 + (lane & 15);
                int seg = ks * 4 + (lane >> 4);
                af[mf] = *reinterpret_cast<const bf16x8*>(Al + rr * 128 + ((seg ^ (rr & 7)) << 4));
            }
#pragma unroll
            for (int nf = 0; nf < 4; nf++) {
                int rr = wn * 64 + nf * 16 + (lane & 15);
                int seg = ks * 4 + (lane >> 4);
                bfr[nf] = *reinterpret_cast<const bf16x8*>(Bl + rr * 128 + ((seg ^ (rr & 7)) << 4));
            }
#pragma unroll
            for (int mf = 0; mf < 4; mf++)
#pragma unroll
                for (int nf = 0; nf < 4; nf++)
                    acc[mf][nf] = __builtin_amdgcn_mfma_f32_16x16x32_bf16(af[mf], bfr[nf], acc[mf][nf], 0, 0, 0);
        }
        __syncthreads();
    }

    // ---- epilogue: acc -> swizzled LDS C-tile [128 rows x 256 B] ----
    char* const Cl = lds;
#pragma unroll
    for (int mf = 0; mf < 4; mf++)
#pragma unroll
        for (int nf = 0; nf < 4; nf++)
#pragma unroll
            for (int r = 0; r < 4; r++) {
                int row = wm * 64 + mf * 16 + (lane >> 4) * 4 + r;
                int col = wn * 64 + nf * 16 + (lane & 15);
                float v = acc[mf][nf][r];
                if (MODE == 0) v += bias[col0 + col];
                *reinterpret_cast<unsigned short*>(Cl + row * 256 + ((col * 2) ^ ((row & 7) << 4))) = f2b(v);
            }
    __syncthreads();

    // ---- read back coalesced: 4 passes x 32 B/thread; thread's 16 cols fixed = (tid&7)*16 ----
    float s[16], q[16], scv[16], shv[16];
    if (MODE == 0) {
#pragma unroll
        for (int j = 0; j < 16; j++) { s[j] = 0.f; q[j] = 0.f; }
    } else {
        int cb = col0 + (tid & 7) * 16;
#pragma unroll
        for (int j = 0; j < 16; j++) { scv[j] = scale[cb + j]; shv[j] = shift[cb + j]; }
    }
#pragma unroll
    for (int p = 0; p < 4; p++) {
        int ch = p * 256 + tid;
        int row = ch >> 3, sg = ch & 7;
        int grow = row0 + row;
        uint4 a0 = *reinterpret_cast<const uint4*>(Cl + row * 256 + (((sg * 2)     ^ (row & 7)) << 4));
        uint4 a1 = *reinterpret_cast<const uint4*>(Cl + row * 256 + (((sg * 2 + 1) ^ (row & 7)) << 4));
        if (grow < M) {
            unsigned short* u0 = reinterpret_cast<unsigned short*>(&a0);
            unsigned short* u1 = reinterpret_cast<unsigned short*>(&a1);
            if (MODE == 0) {
#pragma unroll
                for (int j = 0; j < 8; j++) { float f = b2f(u0[j]); s[j] += f; q[j] += f * f; }
#pragma unroll
                for (int j = 0; j < 8; j++) { float f = b2f(u1[j]); s[8 + j] += f; q[8 + j] += f * f; }
                uint4* dst = reinterpret_cast<uint4*>(C + (size_t)grow * HD + col0 + sg * 16);
                dst[0] = a0; dst[1] = a1;
            } else {
                const uint4* agp = reinterpret_cast<const uint4*>(aggin + (size_t)grow * HD + col0 + sg * 16);
                uint4 g0 = agp[0], g1 = agp[1];
                unsigned short* v0 = reinterpret_cast<unsigned short*>(&g0);
                unsigned short* v1 = reinterpret_cast<unsigned short*>(&g1);
                uint4 o0, o1;
                unsigned short* w0 = reinterpret_cast<unsigned short*>(&o0);
                unsigned short* w1 = reinterpret_cast<unsigned short*>(&o1);
#pragma unroll
                for (int j = 0; j < 8; j++)
                    w0[j] = f2b(fmaxf(fmaf(b2f(v0[j]), scv[j], shv[j]), 0.f) + b2f(u0[j]));
#pragma unroll
                for (int j = 0; j < 8; j++)
                    w1[j] = f2b(fmaxf(fmaf(b2f(v1[j]), scv[8 + j], shv[8 + j]), 0.f) + b2f(u1[j]));
                uint4* dst = reinterpret_cast<uint4*>(C + (size_t)grow * HD + col0 + sg * 16);
                dst[0] = o0; dst[1] = o1;
            }
        }
    }

    if (MODE == 0) {
        int cb = (tid & 7) * 16;
#pragma unroll
        for (int j = 0; j < 16; j++) atomicAdd(&sstat[cb + j], s[j]);
#pragma unroll
        for (int j = 0; j < 16; j++) atomicAdd(&sstat[128 + cb + j], q[j]);
        __syncthreads();
        float v = sstat[tid];
        int c = tid & 127;
        if (tid < 128) atomicAdd(&sums[col0 + c], v);
        else           atomicAdd(&sums[256 + col0 + c], v);
    }
}

// ---------------- BatchNorm finalize + epilogue ----------------

__global__ void bn_fin_k(const float* __restrict__ sums, const float* __restrict__ g,
                         const float* __restrict__ be, float* __restrict__ sc, float* __restrict__ sh) {
    int c = threadIdx.x;
    float m = sums[c] * (1.0f / NN);
    float v = sums[HD + c] * (1.0f / NN) - m * m;
    float s = g[c] * rsqrtf(v + BNEPS);
    sc[c] = s;
    sh[c] = be[c] - m * s;
}

__global__ __launch_bounds__(256) void epi_k(const unsigned short* __restrict__ agg,
                                             const unsigned short* __restrict__ res,
                                             const float* __restrict__ scp, const float* __restrict__ shp,
                                             unsigned short* __restrict__ out) {
    const size_t total = (size_t)NN * (HD / 4);
    size_t i = (size_t)blockIdx.x * 256 + threadIdx.x;
    const size_t stride = (size_t)gridDim.x * 256;
    for (; i < total; i += stride) {
        int cq = ((int)(i & 63)) * 4;
        float4 a = ld4v(agg + i * 4);
        float4 r = ld4v(res + i * 4);
        float4 sc = *reinterpret_cast<const float4*>(scp + cq);
        float4 sh = *reinterpret_cast<const float4*>(shp + cq);
        float4 o;
        o.x = fmaxf(fmaf(a.x, sc.x, sh.x), 0.f) + r.x;
        o.y = fmaxf(fmaf(a.y, sc.y, sh.y), 0.f) + r.y;
        o.z = fmaxf(fmaf(a.z, sc.z, sh.z), 0.f) + r.z;
        o.w = fmaxf(fmaf(a.w, sc.w, sh.w), 0.f) + r.w;
        st4v(out + i * 4, o);
    }
}

// ---------------- pooling head ----------------

__global__ __launch_bounds__(256) void pool_sum_k(const unsigned short* __restrict__ h,
                                                  const int* __restrict__ batch,
                                                  float* __restrict__ pooled) {
    const int c = threadIdx.x;
    const int rs = blockIdx.x * 256;
    if (rs >= NN) return;
    const int re = min(rs + 256, NN);
    float acc = 0.f;
    int cur = batch[rs];
    for (int r = rs; r < re; r++) {
        int g = batch[r];
        if (g != cur) { atomicAdd(&pooled[(size_t)cur * HD + c], acc); acc = 0.f; cur = g; }
        acc += ld1(h + (size_t)r * HD + c);
    }
    atomicAdd(&pooled[(size_t)cur * HD + c], acc);
}

__global__ void pool_out_k(const float* __restrict__ pooled, const int* __restrict__ batch,
                           const float* __restrict__ Wl, const float* __restrict__ bl,
                           float* __restrict__ out) {
    int g = threadIdx.x;
    if (g < NG) {
        auto lb = [&](int val) {
            int lo = 0, hi = NN;
            while (lo < hi) { int mid = (lo + hi) >> 1; if (batch[mid] < val) lo = mid + 1; else hi = mid; }
            return lo;
        };
        int c0 = lb(g), c1 = lb(g + 1);
        float cn = fmaxf((float)(c1 - c0), 1.0f);
        float s = 0.f;
        for (int c = 0; c < HD; c++) s += pooled[(size_t)g * HD + c] * Wl[c];
        out[g] = s / cn + bl[0];
    }
}

// ---------------- launcher ----------------

static inline size_t alignup(size_t x) { return (x + 255) & ~size_t(255); }

extern "C" void kernel_launch(void* const* d_in, const int* in_sizes, int n_in,
                              void* d_out, int out_size, void* d_ws, size_t ws_size,
                              hipStream_t stream) {
    const float* x    = (const float*)d_in[0];
    const int*   ei   = (const int*)d_in[1];
    const int*   bat  = (const int*)d_in[2];
    const float* W1   = (const float*)d_in[3];
    const float* bi1  = (const float*)d_in[4];
    const float* g1   = (const float*)d_in[5];
    const float* be1  = (const float*)d_in[6];
    const float* P1   = (const float*)d_in[7];
    const float* W2   = (const float*)d_in[8];
    const float* bi2  = (const float*)d_in[9];
    const float* g2   = (const float*)d_in[10];
    const float* be2  = (const float*)d_in[11];
    const float* W3   = (const float*)d_in[12];
    const float* bi3  = (const float*)d_in[13];
    const float* g3   = (const float*)d_in[14];
    const float* be3  = (const float*)d_in[15];
    const float* W4   = (const float*)d_in[16];
    const float* bi4  = (const float*)d_in[17];
    const float* g4   = (const float*)d_in[18];
    const float* be4  = (const float*)d_in[19];
    const float* Wl   = (const float*)d_in[20];
    const float* bl   = (const float*)d_in[21];
    float* out = (float*)d_out;

    const int* e_src = ei;
    const int* e_dst = ei + NE;

    typedef unsigned short ST;
    char* p = (char*)d_ws;
    auto alloc = [&](size_t bytes) { char* q = p; p += alignup(bytes); return q; };
    ST*    fb0     = (ST*)alloc((size_t)NN * HD * sizeof(ST));
    ST*    fb1     = (ST*)alloc((size_t)NN * HD * sizeof(ST));
    ST*    fb2     = (ST*)alloc((size_t)NN * HD * sizeof(ST));
    ST*    xb      = (ST*)alloc((size_t)NN * FIN * sizeof(ST));
    float* dis     = (float*)alloc((size_t)NN * 4);
    float* selfw   = (float*)alloc((size_t)NN * 4);
    int*   rowptr  = (int*)alloc((size_t)(NN + 1) * 4);
    int2*  csr     = (int2*)alloc((size_t)NE * 8);
    int*   partials= (int*)alloc(128 * 4);
    float* bnsc    = (float*)alloc(HD * 4);
    float* bnsh    = (float*)alloc(HD * 4);
    ST*    w1t     = (ST*)alloc(256 * 128 * sizeof(ST));
    ST*    p1t     = (ST*)alloc(256 * 128 * sizeof(ST));
    ST*    w2t     = (ST*)alloc(256 * 256 * sizeof(ST));
    ST*    w3t     = (ST*)alloc(256 * 256 * sizeof(ST));
    ST*    w4t     = (ST*)alloc(256 * 256 * sizeof(ST));
    // ---- single zeroed region: cnt | cursor | sums[4] | pooled ----
    size_t zbytes = (size_t)NN * 4 + (size_t)NN * 4 + 4 * 2 * HD * 4 + (size_t)NG * HD * 4;
    char*  zbase   = alloc(zbytes);
    int*   cnt     = (int*)zbase;
    int*   cursor  = (int*)(zbase + (size_t)NN * 4);
    float* sums1   = (float*)(zbase + (size_t)NN * 8);
    float* sums2   = sums1 + 2 * HD;
    float* sums3   = sums2 + 2 * HD;
    float* sums4   = sums3 + 2 * HD;
    float* pooled  = sums4 + 2 * HD;

    const int NB = (NN + 1023) / 1024;  // 98
    dim3 gg((NN + 127) / 128, 2);       // 782 x 2 gemm blocks

    hipMemsetAsync(zbase, 0, zbytes, stream);

    // ---- weight/x prep ----
    wt_all_k<<<1024, 256, 0, stream>>>(W1, P1, W2, W3, W4, w1t, p1t, w2t, w3t, w4t);
    x2b_k<<<(NN * FIN / 4 + 255) / 256, 256, 0, stream>>>(x, xb);

    // ---- graph preprocessing ----
    count_deg_k<<<(NE + 255) / 256, 256, 0, stream>>>(e_dst, cnt);
    node_prep_k<<<(NN + 255) / 256, 256, 0, stream>>>(cnt, dis, selfw);
    scan_reduce_k<<<NB, 1024, 0, stream>>>(cnt, partials);
    scan_partials_k<<<1, 64, 0, stream>>>(partials, NB);
    scan_write_k<<<NB, 1024, 0, stream>>>(cnt, partials, rowptr);
    fill_csr_k<<<(NE + 255) / 256, 256, 0, stream>>>(e_src, e_dst, rowptr, cursor, dis, csr);

    // ---- block 1 (x:128 -> 256, projection residual) ----
    spmm_k<128><<<NN / 4, 256, 0, stream>>>(xb, rowptr, csr, selfw, fb0);
    mgemm_k<128, 0><<<gg, 256, 0, stream>>>(fb0, w1t, bi1, fb2, nullptr, nullptr, nullptr, sums1, NN);
    bn_fin_k<<<1, 256, 0, stream>>>(sums1, g1, be1, bnsc, bnsh);
    mgemm_k<128, 1><<<gg, 256, 0, stream>>>(xb, p1t, nullptr, fb1, bnsc, bnsh, fb2, nullptr, NN);
    // h1 = fb1

    // ---- block 2 ----
    spmm_k<256><<<NN / 4, 256, 0, stream>>>(fb1, rowptr, csr, selfw, fb0);
    mgemm_k<256, 0><<<gg, 256, 0, stream>>>(fb0, w2t, bi2, fb2, nullptr, nullptr, nullptr, sums2, NN);
    bn_fin_k<<<1, 256, 0, stream>>>(sums2, g2, be2, bnsc, bnsh);
    epi_k<<<4096, 256, 0, stream>>>(fb2, fb1, bnsc, bnsh, fb0);
    // h2 = fb0

    // ---- block 3 ----
    spmm_k<256><<<NN / 4, 256, 0, stream>>>(fb0, rowptr, csr, selfw, fb1);
    mgemm_k<256, 0><<<gg, 256, 0, stream>>>(fb1, w3t, bi3, fb2, nullptr, nullptr, nullptr, sums3, NN);
    bn_fin_k<<<1, 256, 0, stream>>>(sums3, g3, be3, bnsc, bnsh);
    epi_k<<<4096, 256, 0, stream>>>(fb2, fb0, bnsc, bnsh, fb1);
    // h3 = fb1

    // ---- block 4 ----
    spmm_k<256><<<NN / 4, 256, 0, stream>>>(fb1, rowptr, csr, selfw, fb0);
    mgemm_k<256, 0><<<gg, 256, 0, stream>>>(fb0, w4t, bi4, fb2, nullptr, nullptr, nullptr, sums4, NN);
    bn_fin_k<<<1, 256, 0, stream>>>(sums4, g4, be4, bnsc, bnsh);
    epi_k<<<4096, 256, 0, stream>>>(fb2, fb1, bnsc, bnsh, fb0);
    // h4 = fb0

    // ---- pooling head ----
    pool_sum_k<<<(NN + 255) / 256, 256, 0, stream>>>(fb0, bat, pooled);
    pool_out_k<<<1, 64, 0, stream>>>(pooled, bat, Wl, bl, out);
}

// Round 8
// 857.136 us; speedup vs baseline: 1.1978x; 1.1978x over previous
//
#include <hip/hip_runtime.h>
#include <cstdint>
#include <cstddef>

#define NN 100000
#define NE 1000000
#define FIN 128
#define HD 256
#define NG 64
#define BNEPS 1e-5f

typedef unsigned short ushort_t;
typedef __attribute__((ext_vector_type(8))) short bf16x8;
typedef __attribute__((ext_vector_type(4))) float f32x4;

// ---------- bf16<->f32 helpers (storage is raw bf16 bits in ushort) ----------

__device__ inline float b2f(unsigned short u) {
    union { float f; unsigned int i; } x; x.i = ((unsigned int)u) << 16; return x.f;
}
__device__ inline unsigned short f2b(float f) {
    union { float f; unsigned int i; } x; x.f = f;
    unsigned int r = x.i + 0x7FFFu + ((x.i >> 16) & 1u);
    return (unsigned short)(r >> 16);
}
__device__ inline float  ld1(const unsigned short* p) { return b2f(*p); }
__device__ inline float4 ld4v(const unsigned short* p) {
    ushort4 u = *(const ushort4*)p;
    return make_float4(b2f(u.x), b2f(u.y), b2f(u.z), b2f(u.w));
}
__device__ inline float2 ld2v(const unsigned short* p) {
    ushort2 u = *(const ushort2*)p;
    return make_float2(b2f(u.x), b2f(u.y));
}
__device__ inline void st4v(unsigned short* p, float4 v) {
    ushort4 u; u.x = f2b(v.x); u.y = f2b(v.y); u.z = f2b(v.z); u.w = f2b(v.w);
    *(ushort4*)p = u;
}
__device__ inline void st2v(unsigned short* p, float2 v) {
    ushort2 u; u.x = f2b(v.x); u.y = f2b(v.y);
    *(ushort2*)p = u;
}

// ---------------- graph preprocessing ----------------

__global__ __launch_bounds__(256) void count_deg_k(const int* __restrict__ dst, int* __restrict__ cnt) {
    int e = blockIdx.x * 256 + threadIdx.x;
    if (e < NE) atomicAdd(&cnt[dst[e]], 1);
}

__global__ __launch_bounds__(256) void node_prep_k(const int* __restrict__ cnt,
                                                   float* __restrict__ dis, float* __restrict__ selfw) {
    int i = blockIdx.x * 256 + threadIdx.x;
    if (i < NN) {
        float d = (float)cnt[i] + 1.0f;
        dis[i] = rsqrtf(d);
        selfw[i] = 1.0f / d;
    }
}

__global__ __launch_bounds__(1024) void scan_reduce_k(const int* __restrict__ cnt, int* __restrict__ partials) {
    __shared__ int sh[1024];
    int i = blockIdx.x * 1024 + threadIdx.x;
    sh[threadIdx.x] = (i < NN) ? cnt[i] : 0;
    __syncthreads();
    for (int off = 512; off > 0; off >>= 1) {
        if (threadIdx.x < off) sh[threadIdx.x] += sh[threadIdx.x + off];
        __syncthreads();
    }
    if (threadIdx.x == 0) partials[blockIdx.x] = sh[0];
}

__global__ void scan_partials_k(int* partials, int nb) {
    if (threadIdx.x == 0 && blockIdx.x == 0) {
        int run = 0;
        for (int b = 0; b < nb; b++) { int v = partials[b]; partials[b] = run; run += v; }
    }
}

__global__ __launch_bounds__(1024) void scan_write_k(const int* __restrict__ cnt,
                                                     const int* __restrict__ partials,
                                                     int* __restrict__ rowptr) {
    __shared__ int sh[1024];
    int i = blockIdx.x * 1024 + threadIdx.x;
    int v = (i < NN) ? cnt[i] : 0;
    sh[threadIdx.x] = v;
    __syncthreads();
    for (int off = 1; off < 1024; off <<= 1) {
        int t = (threadIdx.x >= off) ? sh[threadIdx.x - off] : 0;
        __syncthreads();
        sh[threadIdx.x] += t;
        __syncthreads();
    }
    if (i < NN) rowptr[i] = partials[blockIdx.x] + sh[threadIdx.x] - v;
    if (i == NN - 1) rowptr[NN] = partials[blockIdx.x] + sh[threadIdx.x];
}

// CSR packed as int2 {src, weight_bits}: one 8B load per edge in the SpMM.
__global__ __launch_bounds__(256) void fill_csr_k(const int* __restrict__ src, const int* __restrict__ dst,
                                                  const int* __restrict__ rowptr, int* __restrict__ cursor,
                                                  const float* __restrict__ dis,
                                                  int2* __restrict__ csr) {
    int e = blockIdx.x * 256 + threadIdx.x;
    if (e < NE) {
        int d = dst[e], s = src[e];
        int pos = rowptr[d] + atomicAdd(&cursor[d], 1);
        float w = dis[s] * dis[d];
        csr[pos] = make_int2(s, __float_as_int(w));
    }
}

// ---- x (fp32 [N,128]) -> bf16 ----
__global__ __launch_bounds__(256) void x2b_k(const float* __restrict__ x, unsigned short* __restrict__ xb) {
    int i = blockIdx.x * 256 + threadIdx.x;
    if (i < NN * FIN / 4) {
        float4 v = *reinterpret_cast<const float4*>(x + (size_t)i * 4);
        ushort4 u; u.x = f2b(v.x); u.y = f2b(v.y); u.z = f2b(v.z); u.w = f2b(v.w);
        *reinterpret_cast<ushort4*>(xb + (size_t)i * 4) = u;
    }
}

// ---- weight prep, all 5 in one launch: W[K][256] fp32 -> Bt[256][K] bf16 ----
__global__ __launch_bounds__(256) void wt_all_k(const float* __restrict__ W1, const float* __restrict__ P1,
                                                const float* __restrict__ W2, const float* __restrict__ W3,
                                                const float* __restrict__ W4,
                                                unsigned short* __restrict__ w1t, unsigned short* __restrict__ p1t,
                                                unsigned short* __restrict__ w2t, unsigned short* __restrict__ w3t,
                                                unsigned short* __restrict__ w4t) {
    int b = blockIdx.x;
    const float* W; unsigned short* Bt; int K; int base;
    if (b < 128)      { W = W1; Bt = w1t; K = 128; base = b; }
    else if (b < 256) { W = P1; Bt = p1t; K = 128; base = b - 128; }
    else if (b < 512) { W = W2; Bt = w2t; K = 256; base = b - 256; }
    else if (b < 768) { W = W3; Bt = w3t; K = 256; base = b - 512; }
    else              { W = W4; Bt = w4t; K = 256; base = b - 768; }
    int i = base * 256 + threadIdx.x;
    if (i < K * 256) {
        int k = i >> 8, n = i & 255;
        Bt[n * K + k] = f2b(W[k * 256 + n]);
    }
}

// ---------------- SpMM: z[i,:] = selfw[i]*h[i,:] + sum_e w_e * h[src_e,:] ----------------

template<int COLS>
__global__ __launch_bounds__(256) void spmm_k(const unsigned short* __restrict__ h,
                                              const int* __restrict__ rowptr,
                                              const int2* __restrict__ csr,
                                              const float* __restrict__ selfw,
                                              unsigned short* __restrict__ z) {
    const int lane = threadIdx.x & 63;
    const int row = blockIdx.x * 4 + (threadIdx.x >> 6);
    if (row >= NN) return;
    if constexpr (COLS == 256) {
        float4 a = ld4v(h + (size_t)row * COLS + lane * 4);
        float sw = selfw[row];
        float4 acc = make_float4(a.x * sw, a.y * sw, a.z * sw, a.w * sw);
        int e = rowptr[row];
        const int e1 = rowptr[row + 1];
        for (; e + 4 <= e1; e += 4) {
            int2 c0 = csr[e], c1 = csr[e + 1], c2 = csr[e + 2], c3 = csr[e + 3];
            float4 h0 = ld4v(h + (size_t)c0.x * COLS + lane * 4);
            float4 h1 = ld4v(h + (size_t)c1.x * COLS + lane * 4);
            float4 h2 = ld4v(h + (size_t)c2.x * COLS + lane * 4);
            float4 h3 = ld4v(h + (size_t)c3.x * COLS + lane * 4);
            float w0 = __int_as_float(c0.y), w1 = __int_as_float(c1.y);
            float w2 = __int_as_float(c2.y), w3 = __int_as_float(c3.y);
            acc.x += w0 * h0.x; acc.y += w0 * h0.y; acc.z += w0 * h0.z; acc.w += w0 * h0.w;
            acc.x += w1 * h1.x; acc.y += w1 * h1.y; acc.z += w1 * h1.z; acc.w += w1 * h1.w;
            acc.x += w2 * h2.x; acc.y += w2 * h2.y; acc.z += w2 * h2.z; acc.w += w2 * h2.w;
            acc.x += w3 * h3.x; acc.y += w3 * h3.y; acc.z += w3 * h3.z; acc.w += w3 * h3.w;
        }
        for (; e < e1; e++) {
            int2 c = csr[e];
            float w = __int_as_float(c.y);
            float4 hv = ld4v(h + (size_t)c.x * COLS + lane * 4);
            acc.x += w * hv.x; acc.y += w * hv.y; acc.z += w * hv.z; acc.w += w * hv.w;
        }
        st4v(z + (size_t)row * COLS + lane * 4, acc);
    } else {
        float2 a = ld2v(h + (size_t)row * COLS + lane * 2);
        float sw = selfw[row];
        float2 acc = make_float2(a.x * sw, a.y * sw);
        int e = rowptr[row];
        const int e1 = rowptr[row + 1];
        for (; e + 4 <= e1; e += 4) {
            int2 c0 = csr[e], c1 = csr[e + 1], c2 = csr[e + 2], c3 = csr[e + 3];
            float2 h0 = ld2v(h + (size_t)c0.x * COLS + lane * 2);
            float2 h1 = ld2v(h + (size_t)c1.x * COLS + lane * 2);
            float2 h2 = ld2v(h + (size_t)c2.x * COLS + lane * 2);
            float2 h3 = ld2v(h + (size_t)c3.x * COLS + lane * 2);
            float w0 = __int_as_float(c0.y), w1 = __int_as_float(c1.y);
            float w2 = __int_as_float(c2.y), w3 = __int_as_float(c3.y);
            acc.x += w0 * h0.x; acc.y += w0 * h0.y;
            acc.x += w1 * h1.x; acc.y += w1 * h1.y;
            acc.x += w2 * h2.x; acc.y += w2 * h2.y;
            acc.x += w3 * h3.x; acc.y += w3 * h3.y;
        }
        for (; e < e1; e++) {
            int2 c = csr[e];
            float w = __int_as_float(c.y);
            float2 hv = ld2v(h + (size_t)c.x * COLS + lane * 2);
            acc.x += w * hv.x; acc.y += w * hv.y;
        }
        st2v(z + (size_t)row * COLS + lane * 2, acc);
    }
}

// ---------------- MFMA bf16 GEMM, barrier-free streaming structure ----------------
// B-half (NCOLS=128 cols x K) lives entirely in LDS (loaded once, one barrier).
// 512 threads = 8 waves; each wave independently owns 32 rows x 128 cols:
// A streams global->VGPR (no LDS, no barriers), B-frags from swizzled LDS.
// Swapped-operand MFMA: acc regs = 4 consecutive C-cols of one row -> packed 8B stores.
// MODE 0: C = A@B + bias, fused per-column BN sums (s, s^2). MODE 1: relu-residual epilogue.

template<int K, int MODE>
__global__ __launch_bounds__(512) void mgemm_k(const unsigned short* __restrict__ A,
                                               const unsigned short* __restrict__ Bt,
                                               const float* __restrict__ bias,
                                               unsigned short* __restrict__ C,
                                               const float* __restrict__ scale,
                                               const float* __restrict__ shift,
                                               const unsigned short* __restrict__ aggin,
                                               float* __restrict__ sums, int M) {
    constexpr int NCOLS = 128;
    constexpr int NF = NCOLS / 16;            // 8 col-tiles per wave
    constexpr int SEGS = K / 8;               // 16B segments per B column
    __shared__ char Bl[NCOLS * K * 2];        // swizzled [col][K]
    __shared__ float sstat[2 * NCOLS];
    const int tid  = threadIdx.x;
    const int lane = tid & 63;
    const int wid  = tid >> 6;                // 0..7
    const int q    = lane >> 4;               // 0..3  (k-quarter / col-quarter)
    const int rl   = lane & 15;               // row-within-16
    const int col0 = blockIdx.y * NCOLS;
    const int row0 = blockIdx.x * 256 + wid * 32;

    // ---- stage B-half into LDS (swizzled 16B segs), once ----
    for (int s = tid; s < NCOLS * SEGS; s += 512) {
        int col = s / SEGS, j = s % SEGS;
        uint4 v = *reinterpret_cast<const uint4*>(Bt + (size_t)(col0 + col) * K + j * 8);
        *reinterpret_cast<uint4*>(Bl + col * (K * 2) + (((j) ^ (col & 7)) << 4)) = v;
    }
    if (MODE == 0 && tid < 2 * NCOLS) sstat[tid] = 0.f;
    __syncthreads();

    // ---- main loop: barrier-free, per-wave independent ----
    f32x4 acc[2][NF];
#pragma unroll
    for (int m = 0; m < 2; m++)
#pragma unroll
        for (int n = 0; n < NF; n++) acc[m][n] = (f32x4){0.f, 0.f, 0.f, 0.f};

    const int a0r = min(row0 + rl, M - 1);
    const int a1r = min(row0 + 16 + rl, M - 1);
    const unsigned short* pa0 = A + (size_t)a0r * K + q * 8;
    const unsigned short* pa1 = A + (size_t)a1r * K + q * 8;

#pragma unroll
    for (int ks = 0; ks < K / 32; ks++) {
        bf16x8 af0 = *reinterpret_cast<const bf16x8*>(pa0 + ks * 32);
        bf16x8 af1 = *reinterpret_cast<const bf16x8*>(pa1 + ks * 32);
#pragma unroll
        for (int nf = 0; nf < NF; nf++) {
            int col = nf * 16 + rl;
            bf16x8 bf = *reinterpret_cast<const bf16x8*>(Bl + col * (K * 2) + (((ks * 4 + q) ^ (col & 7)) << 4));
            // swapped operands: D tile is C^T -> lane holds (row = A-row rl, 4 consecutive C-cols)
            acc[0][nf] = __builtin_amdgcn_mfma_f32_16x16x32_bf16(bf, af0, acc[0][nf], 0, 0, 0);
            acc[1][nf] = __builtin_amdgcn_mfma_f32_16x16x32_bf16(bf, af1, acc[1][nf], 0, 0, 0);
        }
    }

    // ---- epilogue: per-lane rows row0+rl / row0+16+rl, cols cb..cb+3 ----
    const int g0 = row0 + rl, g1 = row0 + 16 + rl;
    const bool ok0 = g0 < M, ok1 = g1 < M;
#pragma unroll
    for (int nf = 0; nf < NF; nf++) {
        int cb = col0 + nf * 16 + q * 4;
        f32x4 v0 = acc[0][nf], v1 = acc[1][nf];
        if (MODE == 0) {
            float4 bb = *reinterpret_cast<const float4*>(bias + cb);
            v0[0] += bb.x; v0[1] += bb.y; v0[2] += bb.z; v0[3] += bb.w;
            v1[0] += bb.x; v1[1] += bb.y; v1[2] += bb.z; v1[3] += bb.w;
        } else {
            float4 sc = *reinterpret_cast<const float4*>(scale + cb);
            float4 sh = *reinterpret_cast<const float4*>(shift + cb);
            if (ok0) {
                ushort4 ag = *reinterpret_cast<const ushort4*>(aggin + (size_t)g0 * HD + cb);
                v0[0] += fmaxf(fmaf(b2f(ag.x), sc.x, sh.x), 0.f);
                v0[1] += fmaxf(fmaf(b2f(ag.y), sc.y, sh.y), 0.f);
                v0[2] += fmaxf(fmaf(b2f(ag.z), sc.z, sh.z), 0.f);
                v0[3] += fmaxf(fmaf(b2f(ag.w), sc.w, sh.w), 0.f);
            }
            if (ok1) {
                ushort4 ag = *reinterpret_cast<const ushort4*>(aggin + (size_t)g1 * HD + cb);
                v1[0] += fmaxf(fmaf(b2f(ag.x), sc.x, sh.x), 0.f);
                v1[1] += fmaxf(fmaf(b2f(ag.y), sc.y, sh.y), 0.f);
                v1[2] += fmaxf(fmaf(b2f(ag.z), sc.z, sh.z), 0.f);
                v1[3] += fmaxf(fmaf(b2f(ag.w), sc.w, sh.w), 0.f);
            }
        }
        if (ok0) {
            ushort4 u; u.x = f2b(v0[0]); u.y = f2b(v0[1]); u.z = f2b(v0[2]); u.w = f2b(v0[3]);
            *reinterpret_cast<ushort4*>(C + (size_t)g0 * HD + cb) = u;
        }
        if (ok1) {
            ushort4 u; u.x = f2b(v1[0]); u.y = f2b(v1[1]); u.z = f2b(v1[2]); u.w = f2b(v1[3]);
            *reinterpret_cast<ushort4*>(C + (size_t)g1 * HD + cb) = u;
        }
        if (MODE == 0) {
            if (!ok0) { v0[0] = v0[1] = v0[2] = v0[3] = 0.f; }
            if (!ok1) { v1[0] = v1[1] = v1[2] = v1[3] = 0.f; }
            float s[4], qq[4];
#pragma unroll
            for (int j = 0; j < 4; j++) {
                s[j]  = v0[j] + v1[j];
                qq[j] = v0[j] * v0[j] + v1[j] * v1[j];
            }
            // reduce across the 16 row-lanes (rl = lane bits 0..3)
#pragma unroll
            for (int m = 1; m < 16; m <<= 1) {
#pragma unroll
                for (int j = 0; j < 4; j++) {
                    s[j]  += __shfl_xor(s[j], m, 64);
                    qq[j] += __shfl_xor(qq[j], m, 64);
                }
            }
            if (rl == 0) {
                int cl = nf * 16 + q * 4;
#pragma unroll
                for (int j = 0; j < 4; j++) {
                    atomicAdd(&sstat[cl + j], s[j]);
                    atomicAdd(&sstat[NCOLS + cl + j], qq[j]);
                }
            }
        }
    }

    if (MODE == 0) {
        __syncthreads();
        if (tid < NCOLS)            atomicAdd(&sums[col0 + tid], sstat[tid]);
        else if (tid < 2 * NCOLS)   atomicAdd(&sums[HD + col0 + (tid - NCOLS)], sstat[tid]);
    }
}

// ---------------- BatchNorm finalize + epilogue ----------------

__global__ void bn_fin_k(const float* __restrict__ sums, const float* __restrict__ g,
                         const float* __restrict__ be, float* __restrict__ sc, float* __restrict__ sh) {
    int c = threadIdx.x;
    float m = sums[c] * (1.0f / NN);
    float v = sums[HD + c] * (1.0f / NN) - m * m;
    float s = g[c] * rsqrtf(v + BNEPS);
    sc[c] = s;
    sh[c] = be[c] - m * s;
}

__global__ __launch_bounds__(256) void epi_k(const unsigned short* __restrict__ agg,
                                             const unsigned short* __restrict__ res,
                                             const float* __restrict__ scp, const float* __restrict__ shp,
                                             unsigned short* __restrict__ out) {
    const size_t total = (size_t)NN * (HD / 4);
    size_t i = (size_t)blockIdx.x * 256 + threadIdx.x;
    const size_t stride = (size_t)gridDim.x * 256;
    for (; i < total; i += stride) {
        int cq = ((int)(i & 63)) * 4;
        float4 a = ld4v(agg + i * 4);
        float4 r = ld4v(res + i * 4);
        float4 sc = *reinterpret_cast<const float4*>(scp + cq);
        float4 sh = *reinterpret_cast<const float4*>(shp + cq);
        float4 o;
        o.x = fmaxf(fmaf(a.x, sc.x, sh.x), 0.f) + r.x;
        o.y = fmaxf(fmaf(a.y, sc.y, sh.y), 0.f) + r.y;
        o.z = fmaxf(fmaf(a.z, sc.z, sh.z), 0.f) + r.z;
        o.w = fmaxf(fmaf(a.w, sc.w, sh.w), 0.f) + r.w;
        st4v(out + i * 4, o);
    }
}

// ---------------- pooling head ----------------

__global__ __launch_bounds__(256) void pool_sum_k(const unsigned short* __restrict__ h,
                                                  const int* __restrict__ batch,
                                                  float* __restrict__ pooled) {
    const int c = threadIdx.x;
    const int rs = blockIdx.x * 256;
    if (rs >= NN) return;
    const int re = min(rs + 256, NN);
    float acc = 0.f;
    int cur = batch[rs];
    for (int r = rs; r < re; r++) {
        int g = batch[r];
        if (g != cur) { atomicAdd(&pooled[(size_t)cur * HD + c], acc); acc = 0.f; cur = g; }
        acc += ld1(h + (size_t)r * HD + c);
    }
    atomicAdd(&pooled[(size_t)cur * HD + c], acc);
}

__global__ void pool_out_k(const float* __restrict__ pooled, const int* __restrict__ batch,
                           const float* __restrict__ Wl, const float* __restrict__ bl,
                           float* __restrict__ out) {
    int g = threadIdx.x;
    if (g < NG) {
        auto lb = [&](int val) {
            int lo = 0, hi = NN;
            while (lo < hi) { int mid = (lo + hi) >> 1; if (batch[mid] < val) lo = mid + 1; else hi = mid; }
            return lo;
        };
        int c0 = lb(g), c1 = lb(g + 1);
        float cn = fmaxf((float)(c1 - c0), 1.0f);
        float s = 0.f;
        for (int c = 0; c < HD; c++) s += pooled[(size_t)g * HD + c] * Wl[c];
        out[g] = s / cn + bl[0];
    }
}

// ---------------- launcher ----------------

static inline size_t alignup(size_t x) { return (x + 255) & ~size_t(255); }

extern "C" void kernel_launch(void* const* d_in, const int* in_sizes, int n_in,
                              void* d_out, int out_size, void* d_ws, size_t ws_size,
                              hipStream_t stream) {
    const float* x    = (const float*)d_in[0];
    const int*   ei   = (const int*)d_in[1];
    const int*   bat  = (const int*)d_in[2];
    const float* W1   = (const float*)d_in[3];
    const float* bi1  = (const float*)d_in[4];
    const float* g1   = (const float*)d_in[5];
    const float* be1  = (const float*)d_in[6];
    const float* P1   = (const float*)d_in[7];
    const float* W2   = (const float*)d_in[8];
    const float* bi2  = (const float*)d_in[9];
    const float* g2   = (const float*)d_in[10];
    const float* be2  = (const float*)d_in[11];
    const float* W3   = (const float*)d_in[12];
    const float* bi3  = (const float*)d_in[13];
    const float* g3   = (const float*)d_in[14];
    const float* be3  = (const float*)d_in[15];
    const float* W4   = (const float*)d_in[16];
    const float* bi4  = (const float*)d_in[17];
    const float* g4   = (const float*)d_in[18];
    const float* be4  = (const float*)d_in[19];
    const float* Wl   = (const float*)d_in[20];
    const float* bl   = (const float*)d_in[21];
    float* out = (float*)d_out;

    const int* e_src = ei;
    const int* e_dst = ei + NE;

    typedef unsigned short ST;
    char* p = (char*)d_ws;
    auto alloc = [&](size_t bytes) { char* q = p; p += alignup(bytes); return q; };
    ST*    fb0     = (ST*)alloc((size_t)NN * HD * sizeof(ST));
    ST*    fb1     = (ST*)alloc((size_t)NN * HD * sizeof(ST));
    ST*    fb2     = (ST*)alloc((size_t)NN * HD * sizeof(ST));
    ST*    xb      = (ST*)alloc((size_t)NN * FIN * sizeof(ST));
    float* dis     = (float*)alloc((size_t)NN * 4);
    float* selfw   = (float*)alloc((size_t)NN * 4);
    int*   rowptr  = (int*)alloc((size_t)(NN + 1) * 4);
    int2*  csr     = (int2*)alloc((size_t)NE * 8);
    int*   partials= (int*)alloc(128 * 4);
    float* bnsc    = (float*)alloc(HD * 4);
    float* bnsh    = (float*)alloc(HD * 4);
    ST*    w1t     = (ST*)alloc(256 * 128 * sizeof(ST));
    ST*    p1t     = (ST*)alloc(256 * 128 * sizeof(ST));
    ST*    w2t     = (ST*)alloc(256 * 256 * sizeof(ST));
    ST*    w3t     = (ST*)alloc(256 * 256 * sizeof(ST));
    ST*    w4t     = (ST*)alloc(256 * 256 * sizeof(ST));
    // ---- single zeroed region: cnt | cursor | sums[4] | pooled ----
    size_t zbytes = (size_t)NN * 4 + (size_t)NN * 4 + 4 * 2 * HD * 4 + (size_t)NG * HD * 4;
    char*  zbase   = alloc(zbytes);
    int*   cnt     = (int*)zbase;
    int*   cursor  = (int*)(zbase + (size_t)NN * 4);
    float* sums1   = (float*)(zbase + (size_t)NN * 8);
    float* sums2   = sums1 + 2 * HD;
    float* sums3   = sums2 + 2 * HD;
    float* sums4   = sums3 + 2 * HD;
    float* pooled  = sums4 + 2 * HD;

    const int NB = (NN + 1023) / 1024;  // 98
    dim3 gg((NN + 255) / 256, 2);       // 391 x 2 gemm blocks, 512 threads

    hipMemsetAsync(zbase, 0, zbytes, stream);

    // ---- weight/x prep ----
    wt_all_k<<<1024, 256, 0, stream>>>(W1, P1, W2, W3, W4, w1t, p1t, w2t, w3t, w4t);
    x2b_k<<<(NN * FIN / 4 + 255) / 256, 256, 0, stream>>>(x, xb);

    // ---- graph preprocessing ----
    count_deg_k<<<(NE + 255) / 256, 256, 0, stream>>>(e_dst, cnt);
    node_prep_k<<<(NN + 255) / 256, 256, 0, stream>>>(cnt, dis, selfw);
    scan_reduce_k<<<NB, 1024, 0, stream>>>(cnt, partials);
    scan_partials_k<<<1, 64, 0, stream>>>(partials, NB);
    scan_write_k<<<NB, 1024, 0, stream>>>(cnt, partials, rowptr);
    fill_csr_k<<<(NE + 255) / 256, 256, 0, stream>>>(e_src, e_dst, rowptr, cursor, dis, csr);

    // ---- block 1 (x:128 -> 256, projection residual) ----
    spmm_k<128><<<NN / 4, 256, 0, stream>>>(xb, rowptr, csr, selfw, fb0);
    mgemm_k<128, 0><<<gg, 512, 0, stream>>>(fb0, w1t, bi1, fb2, nullptr, nullptr, nullptr, sums1, NN);
    bn_fin_k<<<1, 256, 0, stream>>>(sums1, g1, be1, bnsc, bnsh);
    mgemm_k<128, 1><<<gg, 512, 0, stream>>>(xb, p1t, nullptr, fb1, bnsc, bnsh, fb2, nullptr, NN);
    // h1 = fb1

    // ---- block 2 ----
    spmm_k<256><<<NN / 4, 256, 0, stream>>>(fb1, rowptr, csr, selfw, fb0);
    mgemm_k<256, 0><<<gg, 512, 0, stream>>>(fb0, w2t, bi2, fb2, nullptr, nullptr, nullptr, sums2, NN);
    bn_fin_k<<<1, 256, 0, stream>>>(sums2, g2, be2, bnsc, bnsh);
    epi_k<<<4096, 256, 0, stream>>>(fb2, fb1, bnsc, bnsh, fb0);
    // h2 = fb0

    // ---- block 3 ----
    spmm_k<256><<<NN / 4, 256, 0, stream>>>(fb0, rowptr, csr, selfw, fb1);
    mgemm_k<256, 0><<<gg, 512, 0, stream>>>(fb1, w3t, bi3, fb2, nullptr, nullptr, nullptr, sums3, NN);
    bn_fin_k<<<1, 256, 0, stream>>>(sums3, g3, be3, bnsc, bnsh);
    epi_k<<<4096, 256, 0, stream>>>(fb2, fb0, bnsc, bnsh, fb1);
    // h3 = fb1

    // ---- block 4 ----
    spmm_k<256><<<NN / 4, 256, 0, stream>>>(fb1, rowptr, csr, selfw, fb0);
    mgemm_k<256, 0><<<gg, 512, 0, stream>>>(fb0, w4t, bi4, fb2, nullptr, nullptr, nullptr, sums4, NN);
    bn_fin_k<<<1, 256, 0, stream>>>(sums4, g4, be4, bnsc, bnsh);
    epi_k<<<4096, 256, 0, stream>>>(fb2, fb1, bnsc, bnsh, fb0);
    // h4 = fb0

    // ---- pooling head ----
    pool_sum_k<<<(NN + 255) / 256, 256, 0, stream>>>(fb0, bat, pooled);
    pool_out_k<<<1, 64, 0, stream>>>(pooled, bat, Wl, bl, out);
}

// Round 9
// 846.900 us; speedup vs baseline: 1.2123x; 1.0121x over previous
//
#include <hip/hip_runtime.h>
#include <cstdint>
#include <cstddef>

#define NN 100000
#define NE 1000000
#define FIN 128
#define HD 256
#define NG 64
#define BNEPS 1e-5f

typedef unsigned short ushort_t;
typedef __attribute__((ext_vector_type(8))) short bf16x8;
typedef __attribute__((ext_vector_type(4))) float f32x4;

// ---------- bf16<->f32 helpers (storage is raw bf16 bits in ushort) ----------

__device__ inline float b2f(unsigned short u) {
    union { float f; unsigned int i; } x; x.i = ((unsigned int)u) << 16; return x.f;
}
__device__ inline unsigned short f2b(float f) {
    union { float f; unsigned int i; } x; x.f = f;
    unsigned int r = x.i + 0x7FFFu + ((x.i >> 16) & 1u);
    return (unsigned short)(r >> 16);
}
__device__ inline float  ld1(const unsigned short* p) { return b2f(*p); }
__device__ inline float4 ld4v(const unsigned short* p) {
    ushort4 u = *(const ushort4*)p;
    return make_float4(b2f(u.x), b2f(u.y), b2f(u.z), b2f(u.w));
}
__device__ inline float2 ld2v(const unsigned short* p) {
    ushort2 u = *(const ushort2*)p;
    return make_float2(b2f(u.x), b2f(u.y));
}
__device__ inline void st4v(unsigned short* p, float4 v) {
    ushort4 u; u.x = f2b(v.x); u.y = f2b(v.y); u.z = f2b(v.z); u.w = f2b(v.w);
    *(ushort4*)p = u;
}
__device__ inline void st2v(unsigned short* p, float2 v) {
    ushort2 u; u.x = f2b(v.x); u.y = f2b(v.y);
    *(ushort2*)p = u;
}

// ---------------- graph preprocessing ----------------

__global__ __launch_bounds__(256) void count_deg_k(const int* __restrict__ dst, int* __restrict__ cnt) {
    int e = blockIdx.x * 256 + threadIdx.x;
    if (e < NE) atomicAdd(&cnt[dst[e]], 1);
}

__global__ __launch_bounds__(256) void node_prep_k(const int* __restrict__ cnt,
                                                   float* __restrict__ dis, float* __restrict__ selfw) {
    int i = blockIdx.x * 256 + threadIdx.x;
    if (i < NN) {
        float d = (float)cnt[i] + 1.0f;
        dis[i] = rsqrtf(d);
        selfw[i] = 1.0f / d;
    }
}

__global__ __launch_bounds__(1024) void scan_reduce_k(const int* __restrict__ cnt, int* __restrict__ partials) {
    __shared__ int sh[1024];
    int i = blockIdx.x * 1024 + threadIdx.x;
    sh[threadIdx.x] = (i < NN) ? cnt[i] : 0;
    __syncthreads();
    for (int off = 512; off > 0; off >>= 1) {
        if (threadIdx.x < off) sh[threadIdx.x] += sh[threadIdx.x + off];
        __syncthreads();
    }
    if (threadIdx.x == 0) partials[blockIdx.x] = sh[0];
}

__global__ void scan_partials_k(int* partials, int nb) {
    if (threadIdx.x == 0 && blockIdx.x == 0) {
        int run = 0;
        for (int b = 0; b < nb; b++) { int v = partials[b]; partials[b] = run; run += v; }
    }
}

__global__ __launch_bounds__(1024) void scan_write_k(const int* __restrict__ cnt,
                                                     const int* __restrict__ partials,
                                                     int* __restrict__ rowptr) {
    __shared__ int sh[1024];
    int i = blockIdx.x * 1024 + threadIdx.x;
    int v = (i < NN) ? cnt[i] : 0;
    sh[threadIdx.x] = v;
    __syncthreads();
    for (int off = 1; off < 1024; off <<= 1) {
        int t = (threadIdx.x >= off) ? sh[threadIdx.x - off] : 0;
        __syncthreads();
        sh[threadIdx.x] += t;
        __syncthreads();
    }
    if (i < NN) rowptr[i] = partials[blockIdx.x] + sh[threadIdx.x] - v;
    if (i == NN - 1) rowptr[NN] = partials[blockIdx.x] + sh[threadIdx.x];
}

// CSR packed as int2 {src, weight_bits}: one 8B load per edge in the SpMM.
__global__ __launch_bounds__(256) void fill_csr_k(const int* __restrict__ src, const int* __restrict__ dst,
                                                  const int* __restrict__ rowptr, int* __restrict__ cursor,
                                                  const float* __restrict__ dis,
                                                  int2* __restrict__ csr) {
    int e = blockIdx.x * 256 + threadIdx.x;
    if (e < NE) {
        int d = dst[e], s = src[e];
        int pos = rowptr[d] + atomicAdd(&cursor[d], 1);
        float w = dis[s] * dis[d];
        csr[pos] = make_int2(s, __float_as_int(w));
    }
}

// ---- x (fp32 [N,128]) -> bf16 ----
__global__ __launch_bounds__(256) void x2b_k(const float* __restrict__ x, unsigned short* __restrict__ xb) {
    int i = blockIdx.x * 256 + threadIdx.x;
    if (i < NN * FIN / 4) {
        float4 v = *reinterpret_cast<const float4*>(x + (size_t)i * 4);
        ushort4 u; u.x = f2b(v.x); u.y = f2b(v.y); u.z = f2b(v.z); u.w = f2b(v.w);
        *reinterpret_cast<ushort4*>(xb + (size_t)i * 4) = u;
    }
}

// ---- weight prep, all 5 in one launch: W[K][256] fp32 -> Bt[256][K] bf16 ----
__global__ __launch_bounds__(256) void wt_all_k(const float* __restrict__ W1, const float* __restrict__ P1,
                                                const float* __restrict__ W2, const float* __restrict__ W3,
                                                const float* __restrict__ W4,
                                                unsigned short* __restrict__ w1t, unsigned short* __restrict__ p1t,
                                                unsigned short* __restrict__ w2t, unsigned short* __restrict__ w3t,
                                                unsigned short* __restrict__ w4t) {
    int b = blockIdx.x;
    const float* W; unsigned short* Bt; int K; int base;
    if (b < 128)      { W = W1; Bt = w1t; K = 128; base = b; }
    else if (b < 256) { W = P1; Bt = p1t; K = 128; base = b - 128; }
    else if (b < 512) { W = W2; Bt = w2t; K = 256; base = b - 256; }
    else if (b < 768) { W = W3; Bt = w3t; K = 256; base = b - 512; }
    else              { W = W4; Bt = w4t; K = 256; base = b - 768; }
    int i = base * 256 + threadIdx.x;
    if (i < K * 256) {
        int k = i >> 8, n = i & 255;
        Bt[n * K + k] = f2b(W[k * 256 + n]);
    }
}

// ---------------- SpMM: z[i,:] = selfw[i]*h[i,:] + sum_e w_e * h[src_e,:] ----------------
// Edge loop unrolled x8: 8 outstanding 512B gathers per wave.

template<int COLS>
__global__ __launch_bounds__(256) void spmm_k(const unsigned short* __restrict__ h,
                                              const int* __restrict__ rowptr,
                                              const int2* __restrict__ csr,
                                              const float* __restrict__ selfw,
                                              unsigned short* __restrict__ z) {
    const int lane = threadIdx.x & 63;
    const int row = blockIdx.x * 4 + (threadIdx.x >> 6);
    if (row >= NN) return;
    if constexpr (COLS == 256) {
        float4 a = ld4v(h + (size_t)row * COLS + lane * 4);
        float sw = selfw[row];
        float4 acc = make_float4(a.x * sw, a.y * sw, a.z * sw, a.w * sw);
        int e = rowptr[row];
        const int e1 = rowptr[row + 1];
        for (; e + 8 <= e1; e += 8) {
            int2 cc[8];
#pragma unroll
            for (int j = 0; j < 8; j++) cc[j] = csr[e + j];
            float4 hv[8];
#pragma unroll
            for (int j = 0; j < 8; j++) hv[j] = ld4v(h + (size_t)cc[j].x * COLS + lane * 4);
#pragma unroll
            for (int j = 0; j < 8; j++) {
                float w = __int_as_float(cc[j].y);
                acc.x += w * hv[j].x; acc.y += w * hv[j].y; acc.z += w * hv[j].z; acc.w += w * hv[j].w;
            }
        }
        for (; e + 4 <= e1; e += 4) {
            int2 c0 = csr[e], c1 = csr[e + 1], c2 = csr[e + 2], c3 = csr[e + 3];
            float4 h0 = ld4v(h + (size_t)c0.x * COLS + lane * 4);
            float4 h1 = ld4v(h + (size_t)c1.x * COLS + lane * 4);
            float4 h2 = ld4v(h + (size_t)c2.x * COLS + lane * 4);
            float4 h3 = ld4v(h + (size_t)c3.x * COLS + lane * 4);
            float w0 = __int_as_float(c0.y), w1 = __int_as_float(c1.y);
            float w2 = __int_as_float(c2.y), w3 = __int_as_float(c3.y);
            acc.x += w0 * h0.x; acc.y += w0 * h0.y; acc.z += w0 * h0.z; acc.w += w0 * h0.w;
            acc.x += w1 * h1.x; acc.y += w1 * h1.y; acc.z += w1 * h1.z; acc.w += w1 * h1.w;
            acc.x += w2 * h2.x; acc.y += w2 * h2.y; acc.z += w2 * h2.z; acc.w += w2 * h2.w;
            acc.x += w3 * h3.x; acc.y += w3 * h3.y; acc.z += w3 * h3.z; acc.w += w3 * h3.w;
        }
        for (; e < e1; e++) {
            int2 c = csr[e];
            float w = __int_as_float(c.y);
            float4 hv = ld4v(h + (size_t)c.x * COLS + lane * 4);
            acc.x += w * hv.x; acc.y += w * hv.y; acc.z += w * hv.z; acc.w += w * hv.w;
        }
        st4v(z + (size_t)row * COLS + lane * 4, acc);
    } else {
        float2 a = ld2v(h + (size_t)row * COLS + lane * 2);
        float sw = selfw[row];
        float2 acc = make_float2(a.x * sw, a.y * sw);
        int e = rowptr[row];
        const int e1 = rowptr[row + 1];
        for (; e + 8 <= e1; e += 8) {
            int2 cc[8];
#pragma unroll
            for (int j = 0; j < 8; j++) cc[j] = csr[e + j];
            float2 hv[8];
#pragma unroll
            for (int j = 0; j < 8; j++) hv[j] = ld2v(h + (size_t)cc[j].x * COLS + lane * 2);
#pragma unroll
            for (int j = 0; j < 8; j++) {
                float w = __int_as_float(cc[j].y);
                acc.x += w * hv[j].x; acc.y += w * hv[j].y;
            }
        }
        for (; e + 4 <= e1; e += 4) {
            int2 c0 = csr[e], c1 = csr[e + 1], c2 = csr[e + 2], c3 = csr[e + 3];
            float2 h0 = ld2v(h + (size_t)c0.x * COLS + lane * 2);
            float2 h1 = ld2v(h + (size_t)c1.x * COLS + lane * 2);
            float2 h2 = ld2v(h + (size_t)c2.x * COLS + lane * 2);
            float2 h3 = ld2v(h + (size_t)c3.x * COLS + lane * 2);
            float w0 = __int_as_float(c0.y), w1 = __int_as_float(c1.y);
            float w2 = __int_as_float(c2.y), w3 = __int_as_float(c3.y);
            acc.x += w0 * h0.x; acc.y += w0 * h0.y;
            acc.x += w1 * h1.x; acc.y += w1 * h1.y;
            acc.x += w2 * h2.x; acc.y += w2 * h2.y;
            acc.x += w3 * h3.x; acc.y += w3 * h3.y;
        }
        for (; e < e1; e++) {
            int2 c = csr[e];
            float w = __int_as_float(c.y);
            float2 hv = ld2v(h + (size_t)c.x * COLS + lane * 2);
            acc.x += w * hv.x; acc.y += w * hv.y;
        }
        st2v(z + (size_t)row * COLS + lane * 2, acc);
    }
}

// ---------------- MFMA bf16 GEMM, barrier-free streaming structure ----------------
// B-half (NCOLS=128 cols x K) lives entirely in LDS (loaded once, one barrier).
// 512 threads = 8 waves; each wave independently owns 32 rows x 128 cols.
// A-fragments fully hoisted to registers (16 outstanding global loads/wave) before MFMAs.
// Swapped-operand MFMA: acc regs = 4 consecutive C-cols of one row -> packed 8B stores.
// MODE 0: C = A@B + bias, fused per-column BN sums (s, s^2). MODE 1: relu-residual epilogue.

template<int K, int MODE>
__global__ __launch_bounds__(512) void mgemm_k(const unsigned short* __restrict__ A,
                                               const unsigned short* __restrict__ Bt,
                                               const float* __restrict__ bias,
                                               unsigned short* __restrict__ C,
                                               const float* __restrict__ scale,
                                               const float* __restrict__ shift,
                                               const unsigned short* __restrict__ aggin,
                                               float* __restrict__ sums, int M) {
    constexpr int NCOLS = 128;
    constexpr int NF = NCOLS / 16;            // 8 col-tiles per wave
    constexpr int SEGS = K / 8;               // 16B segments per B column
    constexpr int KS = K / 32;                // MFMA k-steps
    __shared__ char Bl[NCOLS * K * 2];        // swizzled [col][K]
    __shared__ float sstat[2 * NCOLS];
    const int tid  = threadIdx.x;
    const int lane = tid & 63;
    const int wid  = tid >> 6;                // 0..7
    const int q    = lane >> 4;               // 0..3  (k-quarter / col-quarter)
    const int rl   = lane & 15;               // row-within-16
    const int col0 = blockIdx.y * NCOLS;
    const int row0 = blockIdx.x * 256 + wid * 32;

    // ---- stage B-half into LDS (swizzled 16B segs), once ----
    for (int s = tid; s < NCOLS * SEGS; s += 512) {
        int col = s / SEGS, j = s % SEGS;
        uint4 v = *reinterpret_cast<const uint4*>(Bt + (size_t)(col0 + col) * K + j * 8);
        *reinterpret_cast<uint4*>(Bl + col * (K * 2) + (((j) ^ (col & 7)) << 4)) = v;
    }
    if (MODE == 0 && tid < 2 * NCOLS) sstat[tid] = 0.f;
    __syncthreads();

    // ---- hoisted A stream: all fragments in flight at once ----
    const int a0r = min(row0 + rl, M - 1);
    const int a1r = min(row0 + 16 + rl, M - 1);
    const unsigned short* pa0 = A + (size_t)a0r * K + q * 8;
    const unsigned short* pa1 = A + (size_t)a1r * K + q * 8;
    bf16x8 af0[KS], af1[KS];
#pragma unroll
    for (int ks = 0; ks < KS; ks++) {
        af0[ks] = *reinterpret_cast<const bf16x8*>(pa0 + ks * 32);
        af1[ks] = *reinterpret_cast<const bf16x8*>(pa1 + ks * 32);
    }

    f32x4 acc[2][NF];
#pragma unroll
    for (int m = 0; m < 2; m++)
#pragma unroll
        for (int n = 0; n < NF; n++) acc[m][n] = (f32x4){0.f, 0.f, 0.f, 0.f};

#pragma unroll
    for (int ks = 0; ks < KS; ks++) {
#pragma unroll
        for (int nf = 0; nf < NF; nf++) {
            int col = nf * 16 + rl;
            bf16x8 bf = *reinterpret_cast<const bf16x8*>(Bl + col * (K * 2) + (((ks * 4 + q) ^ (col & 7)) << 4));
            // swapped operands: lane holds (row = A-row rl, 4 consecutive C-cols)
            acc[0][nf] = __builtin_amdgcn_mfma_f32_16x16x32_bf16(bf, af0[ks], acc[0][nf], 0, 0, 0);
            acc[1][nf] = __builtin_amdgcn_mfma_f32_16x16x32_bf16(bf, af1[ks], acc[1][nf], 0, 0, 0);
        }
    }

    // ---- epilogue: per-lane rows row0+rl / row0+16+rl, cols cb..cb+3 ----
    const int g0 = row0 + rl, g1 = row0 + 16 + rl;
    const bool ok0 = g0 < M, ok1 = g1 < M;
#pragma unroll
    for (int nf = 0; nf < NF; nf++) {
        int cb = col0 + nf * 16 + q * 4;
        f32x4 v0 = acc[0][nf], v1 = acc[1][nf];
        if (MODE == 0) {
            float4 bb = *reinterpret_cast<const float4*>(bias + cb);
            v0[0] += bb.x; v0[1] += bb.y; v0[2] += bb.z; v0[3] += bb.w;
            v1[0] += bb.x; v1[1] += bb.y; v1[2] += bb.z; v1[3] += bb.w;
        } else {
            float4 sc = *reinterpret_cast<const float4*>(scale + cb);
            float4 sh = *reinterpret_cast<const float4*>(shift + cb);
            if (ok0) {
                ushort4 ag = *reinterpret_cast<const ushort4*>(aggin + (size_t)g0 * HD + cb);
                v0[0] += fmaxf(fmaf(b2f(ag.x), sc.x, sh.x), 0.f);
                v0[1] += fmaxf(fmaf(b2f(ag.y), sc.y, sh.y), 0.f);
                v0[2] += fmaxf(fmaf(b2f(ag.z), sc.z, sh.z), 0.f);
                v0[3] += fmaxf(fmaf(b2f(ag.w), sc.w, sh.w), 0.f);
            }
            if (ok1) {
                ushort4 ag = *reinterpret_cast<const ushort4*>(aggin + (size_t)g1 * HD + cb);
                v1[0] += fmaxf(fmaf(b2f(ag.x), sc.x, sh.x), 0.f);
                v1[1] += fmaxf(fmaf(b2f(ag.y), sc.y, sh.y), 0.f);
                v1[2] += fmaxf(fmaf(b2f(ag.z), sc.z, sh.z), 0.f);
                v1[3] += fmaxf(fmaf(b2f(ag.w), sc.w, sh.w), 0.f);
            }
        }
        if (ok0) {
            ushort4 u; u.x = f2b(v0[0]); u.y = f2b(v0[1]); u.z = f2b(v0[2]); u.w = f2b(v0[3]);
            *reinterpret_cast<ushort4*>(C + (size_t)g0 * HD + cb) = u;
        }
        if (ok1) {
            ushort4 u; u.x = f2b(v1[0]); u.y = f2b(v1[1]); u.z = f2b(v1[2]); u.w = f2b(v1[3]);
            *reinterpret_cast<ushort4*>(C + (size_t)g1 * HD + cb) = u;
        }
        if (MODE == 0) {
            if (!ok0) { v0[0] = v0[1] = v0[2] = v0[3] = 0.f; }
            if (!ok1) { v1[0] = v1[1] = v1[2] = v1[3] = 0.f; }
            float s[4], qq[4];
#pragma unroll
            for (int j = 0; j < 4; j++) {
                s[j]  = v0[j] + v1[j];
                qq[j] = v0[j] * v0[j] + v1[j] * v1[j];
            }
            // reduce across the 16 row-lanes (rl = lane bits 0..3)
#pragma unroll
            for (int m = 1; m < 16; m <<= 1) {
#pragma unroll
                for (int j = 0; j < 4; j++) {
                    s[j]  += __shfl_xor(s[j], m, 64);
                    qq[j] += __shfl_xor(qq[j], m, 64);
                }
            }
            if (rl == 0) {
                int cl = nf * 16 + q * 4;
#pragma unroll
                for (int j = 0; j < 4; j++) {
                    atomicAdd(&sstat[cl + j], s[j]);
                    atomicAdd(&sstat[NCOLS + cl + j], qq[j]);
                }
            }
        }
    }

    if (MODE == 0) {
        __syncthreads();
        if (tid < NCOLS)            atomicAdd(&sums[col0 + tid], sstat[tid]);
        else if (tid < 2 * NCOLS)   atomicAdd(&sums[HD + col0 + (tid - NCOLS)], sstat[tid]);
    }
}

// ---------------- BatchNorm finalize + epilogue ----------------

__global__ void bn_fin_k(const float* __restrict__ sums, const float* __restrict__ g,
                         const float* __restrict__ be, float* __restrict__ sc, float* __restrict__ sh) {
    int c = threadIdx.x;
    float m = sums[c] * (1.0f / NN);
    float v = sums[HD + c] * (1.0f / NN) - m * m;
    float s = g[c] * rsqrtf(v + BNEPS);
    sc[c] = s;
    sh[c] = be[c] - m * s;
}

__global__ __launch_bounds__(256) void epi_k(const unsigned short* __restrict__ agg,
                                             const unsigned short* __restrict__ res,
                                             const float* __restrict__ scp, const float* __restrict__ shp,
                                             unsigned short* __restrict__ out) {
    const size_t total = (size_t)NN * (HD / 4);
    size_t i = (size_t)blockIdx.x * 256 + threadIdx.x;
    const size_t stride = (size_t)gridDim.x * 256;
    for (; i < total; i += stride) {
        int cq = ((int)(i & 63)) * 4;
        float4 a = ld4v(agg + i * 4);
        float4 r = ld4v(res + i * 4);
        float4 sc = *reinterpret_cast<const float4*>(scp + cq);
        float4 sh = *reinterpret_cast<const float4*>(shp + cq);
        float4 o;
        o.x = fmaxf(fmaf(a.x, sc.x, sh.x), 0.f) + r.x;
        o.y = fmaxf(fmaf(a.y, sc.y, sh.y), 0.f) + r.y;
        o.z = fmaxf(fmaf(a.z, sc.z, sh.z), 0.f) + r.z;
        o.w = fmaxf(fmaf(a.w, sc.w, sh.w), 0.f) + r.w;
        st4v(out + i * 4, o);
    }
}

// ---------------- pooling head ----------------

__global__ __launch_bounds__(256) void pool_sum_k(const unsigned short* __restrict__ h,
                                                  const int* __restrict__ batch,
                                                  float* __restrict__ pooled) {
    const int c = threadIdx.x;
    const int rs = blockIdx.x * 256;
    if (rs >= NN) return;
    const int re = min(rs + 256, NN);
    float acc = 0.f;
    int cur = batch[rs];
    for (int r = rs; r < re; r++) {
        int g = batch[r];
        if (g != cur) { atomicAdd(&pooled[(size_t)cur * HD + c], acc); acc = 0.f; cur = g; }
        acc += ld1(h + (size_t)r * HD + c);
    }
    atomicAdd(&pooled[(size_t)cur * HD + c], acc);
}

__global__ void pool_out_k(const float* __restrict__ pooled, const int* __restrict__ batch,
                           const float* __restrict__ Wl, const float* __restrict__ bl,
                           float* __restrict__ out) {
    int g = threadIdx.x;
    if (g < NG) {
        auto lb = [&](int val) {
            int lo = 0, hi = NN;
            while (lo < hi) { int mid = (lo + hi) >> 1; if (batch[mid] < val) lo = mid + 1; else hi = mid; }
            return lo;
        };
        int c0 = lb(g), c1 = lb(g + 1);
        float cn = fmaxf((float)(c1 - c0), 1.0f);
        float s = 0.f;
        for (int c = 0; c < HD; c++) s += pooled[(size_t)g * HD + c] * Wl[c];
        out[g] = s / cn + bl[0];
    }
}

// ---------------- launcher ----------------

static inline size_t alignup(size_t x) { return (x + 255) & ~size_t(255); }

extern "C" void kernel_launch(void* const* d_in, const int* in_sizes, int n_in,
                              void* d_out, int out_size, void* d_ws, size_t ws_size,
                              hipStream_t stream) {
    const float* x    = (const float*)d_in[0];
    const int*   ei   = (const int*)d_in[1];
    const int*   bat  = (const int*)d_in[2];
    const float* W1   = (const float*)d_in[3];
    const float* bi1  = (const float*)d_in[4];
    const float* g1   = (const float*)d_in[5];
    const float* be1  = (const float*)d_in[6];
    const float* P1   = (const float*)d_in[7];
    const float* W2   = (const float*)d_in[8];
    const float* bi2  = (const float*)d_in[9];
    const float* g2   = (const float*)d_in[10];
    const float* be2  = (const float*)d_in[11];
    const float* W3   = (const float*)d_in[12];
    const float* bi3  = (const float*)d_in[13];
    const float* g3   = (const float*)d_in[14];
    const float* be3  = (const float*)d_in[15];
    const float* W4   = (const float*)d_in[16];
    const float* bi4  = (const float*)d_in[17];
    const float* g4   = (const float*)d_in[18];
    const float* be4  = (const float*)d_in[19];
    const float* Wl   = (const float*)d_in[20];
    const float* bl   = (const float*)d_in[21];
    float* out = (float*)d_out;

    const int* e_src = ei;
    const int* e_dst = ei + NE;

    typedef unsigned short ST;
    char* p = (char*)d_ws;
    auto alloc = [&](size_t bytes) { char* q = p; p += alignup(bytes); return q; };
    ST*    fb0     = (ST*)alloc((size_t)NN * HD * sizeof(ST));
    ST*    fb1     = (ST*)alloc((size_t)NN * HD * sizeof(ST));
    ST*    fb2     = (ST*)alloc((size_t)NN * HD * sizeof(ST));
    ST*    xb      = (ST*)alloc((size_t)NN * FIN * sizeof(ST));
    float* dis     = (float*)alloc((size_t)NN * 4);
    float* selfw   = (float*)alloc((size_t)NN * 4);
    int*   rowptr  = (int*)alloc((size_t)(NN + 1) * 4);
    int2*  csr     = (int2*)alloc((size_t)NE * 8);
    int*   partials= (int*)alloc(128 * 4);
    float* bnsc    = (float*)alloc(HD * 4);
    float* bnsh    = (float*)alloc(HD * 4);
    ST*    w1t     = (ST*)alloc(256 * 128 * sizeof(ST));
    ST*    p1t     = (ST*)alloc(256 * 128 * sizeof(ST));
    ST*    w2t     = (ST*)alloc(256 * 256 * sizeof(ST));
    ST*    w3t     = (ST*)alloc(256 * 256 * sizeof(ST));
    ST*    w4t     = (ST*)alloc(256 * 256 * sizeof(ST));
    // ---- single zeroed region: cnt | cursor | sums[4] | pooled ----
    size_t zbytes = (size_t)NN * 4 + (size_t)NN * 4 + 4 * 2 * HD * 4 + (size_t)NG * HD * 4;
    char*  zbase   = alloc(zbytes);
    int*   cnt     = (int*)zbase;
    int*   cursor  = (int*)(zbase + (size_t)NN * 4);
    float* sums1   = (float*)(zbase + (size_t)NN * 8);
    float* sums2   = sums1 + 2 * HD;
    float* sums3   = sums2 + 2 * HD;
    float* sums4   = sums3 + 2 * HD;
    float* pooled  = sums4 + 2 * HD;

    const int NB = (NN + 1023) / 1024;  // 98
    dim3 gg((NN + 255) / 256, 2);       // 391 x 2 gemm blocks, 512 threads

    hipMemsetAsync(zbase, 0, zbytes, stream);

    // ---- weight/x prep ----
    wt_all_k<<<1024, 256, 0, stream>>>(W1, P1, W2, W3, W4, w1t, p1t, w2t, w3t, w4t);
    x2b_k<<<(NN * FIN / 4 + 255) / 256, 256, 0, stream>>>(x, xb);

    // ---- graph preprocessing ----
    count_deg_k<<<(NE + 255) / 256, 256, 0, stream>>>(e_dst, cnt);
    node_prep_k<<<(NN + 255) / 256, 256, 0, stream>>>(cnt, dis, selfw);
    scan_reduce_k<<<NB, 1024, 0, stream>>>(cnt, partials);
    scan_partials_k<<<1, 64, 0, stream>>>(partials, NB);
    scan_write_k<<<NB, 1024, 0, stream>>>(cnt, partials, rowptr);
    fill_csr_k<<<(NE + 255) / 256, 256, 0, stream>>>(e_src, e_dst, rowptr, cursor, dis, csr);

    // ---- block 1 (x:128 -> 256, projection residual) ----
    spmm_k<128><<<NN / 4, 256, 0, stream>>>(xb, rowptr, csr, selfw, fb0);
    mgemm_k<128, 0><<<gg, 512, 0, stream>>>(fb0, w1t, bi1, fb2, nullptr, nullptr, nullptr, sums1, NN);
    bn_fin_k<<<1, 256, 0, stream>>>(sums1, g1, be1, bnsc, bnsh);
    mgemm_k<128, 1><<<gg, 512, 0, stream>>>(xb, p1t, nullptr, fb1, bnsc, bnsh, fb2, nullptr, NN);
    // h1 = fb1

    // ---- block 2 ----
    spmm_k<256><<<NN / 4, 256, 0, stream>>>(fb1, rowptr, csr, selfw, fb0);
    mgemm_k<256, 0><<<gg, 512, 0, stream>>>(fb0, w2t, bi2, fb2, nullptr, nullptr, nullptr, sums2, NN);
    bn_fin_k<<<1, 256, 0, stream>>>(sums2, g2, be2, bnsc, bnsh);
    epi_k<<<4096, 256, 0, stream>>>(fb2, fb1, bnsc, bnsh, fb0);
    // h2 = fb0

    // ---- block 3 ----
    spmm_k<256><<<NN / 4, 256, 0, stream>>>(fb0, rowptr, csr, selfw, fb1);
    mgemm_k<256, 0><<<gg, 512, 0, stream>>>(fb1, w3t, bi3, fb2, nullptr, nullptr, nullptr, sums3, NN);
    bn_fin_k<<<1, 256, 0, stream>>>(sums3, g3, be3, bnsc, bnsh);
    epi_k<<<4096, 256, 0, stream>>>(fb2, fb0, bnsc, bnsh, fb1);
    // h3 = fb1

    // ---- block 4 ----
    spmm_k<256><<<NN / 4, 256, 0, stream>>>(fb1, rowptr, csr, selfw, fb0);
    mgemm_k<256, 0><<<gg, 512, 0, stream>>>(fb0, w4t, bi4, fb2, nullptr, nullptr, nullptr, sums4, NN);
    bn_fin_k<<<1, 256, 0, stream>>>(sums4, g4, be4, bnsc, bnsh);
    epi_k<<<4096, 256, 0, stream>>>(fb2, fb1, bnsc, bnsh, fb0);
    // h4 = fb0

    // ---- pooling head ----
    pool_sum_k<<<(NN + 255) / 256, 256, 0, stream>>>(fb0, bat, pooled);
    pool_out_k<<<1, 64, 0, stream>>>(pooled, bat, Wl, bl, out);
}

// Round 10
// 798.805 us; speedup vs baseline: 1.2853x; 1.0602x over previous
//
#include <hip/hip_runtime.h>
#include <cstdint>
#include <cstddef>

#define NN 100000
#define NE 1000000
#define FIN 128
#define HD 256
#define NG 64
#define BNEPS 1e-5f

typedef unsigned short ushort_t;
typedef __attribute__((ext_vector_type(8))) short bf16x8;
typedef __attribute__((ext_vector_type(4))) float f32x4;

// ---------- bf16<->f32 helpers (storage is raw bf16 bits in ushort) ----------

__device__ inline float b2f(unsigned short u) {
    union { float f; unsigned int i; } x; x.i = ((unsigned int)u) << 16; return x.f;
}
__device__ inline unsigned short f2b(float f) {
    union { float f; unsigned int i; } x; x.f = f;
    unsigned int r = x.i + 0x7FFFu + ((x.i >> 16) & 1u);
    return (unsigned short)(r >> 16);
}
__device__ inline float  ld1(const unsigned short* p) { return b2f(*p); }
__device__ inline float4 ld4v(const unsigned short* p) {
    ushort4 u = *(const ushort4*)p;
    return make_float4(b2f(u.x), b2f(u.y), b2f(u.z), b2f(u.w));
}
__device__ inline float2 ld2v(const unsigned short* p) {
    ushort2 u = *(const ushort2*)p;
    return make_float2(b2f(u.x), b2f(u.y));
}
__device__ inline void st4v(unsigned short* p, float4 v) {
    ushort4 u; u.x = f2b(v.x); u.y = f2b(v.y); u.z = f2b(v.z); u.w = f2b(v.w);
    *(ushort4*)p = u;
}
__device__ inline void st2v(unsigned short* p, float2 v) {
    ushort2 u; u.x = f2b(v.x); u.y = f2b(v.y);
    *(ushort2*)p = u;
}

// ---------------- graph preprocessing ----------------

__global__ __launch_bounds__(256) void count_deg_k(const int* __restrict__ dst, int* __restrict__ cnt) {
    int e = blockIdx.x * 256 + threadIdx.x;
    if (e < NE) atomicAdd(&cnt[dst[e]], 1);
}

__global__ __launch_bounds__(256) void node_prep_k(const int* __restrict__ cnt,
                                                   float* __restrict__ dis, float* __restrict__ selfw) {
    int i = blockIdx.x * 256 + threadIdx.x;
    if (i < NN) {
        float d = (float)cnt[i] + 1.0f;
        dis[i] = rsqrtf(d);
        selfw[i] = 1.0f / d;
    }
}

__global__ __launch_bounds__(1024) void scan_reduce_k(const int* __restrict__ cnt, int* __restrict__ partials) {
    __shared__ int sh[1024];
    int i = blockIdx.x * 1024 + threadIdx.x;
    sh[threadIdx.x] = (i < NN) ? cnt[i] : 0;
    __syncthreads();
    for (int off = 512; off > 0; off >>= 1) {
        if (threadIdx.x < off) sh[threadIdx.x] += sh[threadIdx.x + off];
        __syncthreads();
    }
    if (threadIdx.x == 0) partials[blockIdx.x] = sh[0];
}

__global__ void scan_partials_k(int* partials, int nb) {
    if (threadIdx.x == 0 && blockIdx.x == 0) {
        int run = 0;
        for (int b = 0; b < nb; b++) { int v = partials[b]; partials[b] = run; run += v; }
    }
}

__global__ __launch_bounds__(1024) void scan_write_k(const int* __restrict__ cnt,
                                                     const int* __restrict__ partials,
                                                     int* __restrict__ rowptr) {
    __shared__ int sh[1024];
    int i = blockIdx.x * 1024 + threadIdx.x;
    int v = (i < NN) ? cnt[i] : 0;
    sh[threadIdx.x] = v;
    __syncthreads();
    for (int off = 1; off < 1024; off <<= 1) {
        int t = (threadIdx.x >= off) ? sh[threadIdx.x - off] : 0;
        __syncthreads();
        sh[threadIdx.x] += t;
        __syncthreads();
    }
    if (i < NN) rowptr[i] = partials[blockIdx.x] + sh[threadIdx.x] - v;
    if (i == NN - 1) rowptr[NN] = partials[blockIdx.x] + sh[threadIdx.x];
}

// CSR packed as int2 {src, weight_bits}: one 8B load per edge in the SpMM.
__global__ __launch_bounds__(256) void fill_csr_k(const int* __restrict__ src, const int* __restrict__ dst,
                                                  const int* __restrict__ rowptr, int* __restrict__ cursor,
                                                  const float* __restrict__ dis,
                                                  int2* __restrict__ csr) {
    int e = blockIdx.x * 256 + threadIdx.x;
    if (e < NE) {
        int d = dst[e], s = src[e];
        int pos = rowptr[d] + atomicAdd(&cursor[d], 1);
        float w = dis[s] * dis[d];
        csr[pos] = make_int2(s, __float_as_int(w));
    }
}

// ---- x (fp32 [N,128]) -> bf16 ----
__global__ __launch_bounds__(256) void x2b_k(const float* __restrict__ x, unsigned short* __restrict__ xb) {
    int i = blockIdx.x * 256 + threadIdx.x;
    if (i < NN * FIN / 4) {
        float4 v = *reinterpret_cast<const float4*>(x + (size_t)i * 4);
        ushort4 u; u.x = f2b(v.x); u.y = f2b(v.y); u.z = f2b(v.z); u.w = f2b(v.w);
        *reinterpret_cast<ushort4*>(xb + (size_t)i * 4) = u;
    }
}

// ---- weight prep, all 5 in one launch: W[K][256] fp32 -> Bt[256][K] bf16 ----
__global__ __launch_bounds__(256) void wt_all_k(const float* __restrict__ W1, const float* __restrict__ P1,
                                                const float* __restrict__ W2, const float* __restrict__ W3,
                                                const float* __restrict__ W4,
                                                unsigned short* __restrict__ w1t, unsigned short* __restrict__ p1t,
                                                unsigned short* __restrict__ w2t, unsigned short* __restrict__ w3t,
                                                unsigned short* __restrict__ w4t) {
    int b = blockIdx.x;
    const float* W; unsigned short* Bt; int K; int base;
    if (b < 128)      { W = W1; Bt = w1t; K = 128; base = b; }
    else if (b < 256) { W = P1; Bt = p1t; K = 128; base = b - 128; }
    else if (b < 512) { W = W2; Bt = w2t; K = 256; base = b - 256; }
    else if (b < 768) { W = W3; Bt = w3t; K = 256; base = b - 512; }
    else              { W = W4; Bt = w4t; K = 256; base = b - 768; }
    int i = base * 256 + threadIdx.x;
    if (i < K * 256) {
        int k = i >> 8, n = i & 255;
        Bt[n * K + k] = f2b(W[k * 256 + n]);
    }
}

// ---------------- SpMM: z[i,:] = selfw[i]*h[i,:] + sum_e w_e * h[src_e,:] ----------------

template<int COLS>
__global__ __launch_bounds__(256) void spmm_k(const unsigned short* __restrict__ h,
                                              const int* __restrict__ rowptr,
                                              const int2* __restrict__ csr,
                                              const float* __restrict__ selfw,
                                              unsigned short* __restrict__ z) {
    const int lane = threadIdx.x & 63;
    const int row = blockIdx.x * 4 + (threadIdx.x >> 6);
    if (row >= NN) return;
    if constexpr (COLS == 256) {
        float4 a = ld4v(h + (size_t)row * COLS + lane * 4);
        float sw = selfw[row];
        float4 acc = make_float4(a.x * sw, a.y * sw, a.z * sw, a.w * sw);
        int e = rowptr[row];
        const int e1 = rowptr[row + 1];
        for (; e + 8 <= e1; e += 8) {
            int2 cc[8];
#pragma unroll
            for (int j = 0; j < 8; j++) cc[j] = csr[e + j];
            float4 hv[8];
#pragma unroll
            for (int j = 0; j < 8; j++) hv[j] = ld4v(h + (size_t)cc[j].x * COLS + lane * 4);
#pragma unroll
            for (int j = 0; j < 8; j++) {
                float w = __int_as_float(cc[j].y);
                acc.x += w * hv[j].x; acc.y += w * hv[j].y; acc.z += w * hv[j].z; acc.w += w * hv[j].w;
            }
        }
        for (; e + 4 <= e1; e += 4) {
            int2 c0 = csr[e], c1 = csr[e + 1], c2 = csr[e + 2], c3 = csr[e + 3];
            float4 h0 = ld4v(h + (size_t)c0.x * COLS + lane * 4);
            float4 h1 = ld4v(h + (size_t)c1.x * COLS + lane * 4);
            float4 h2 = ld4v(h + (size_t)c2.x * COLS + lane * 4);
            float4 h3 = ld4v(h + (size_t)c3.x * COLS + lane * 4);
            float w0 = __int_as_float(c0.y), w1 = __int_as_float(c1.y);
            float w2 = __int_as_float(c2.y), w3 = __int_as_float(c3.y);
            acc.x += w0 * h0.x; acc.y += w0 * h0.y; acc.z += w0 * h0.z; acc.w += w0 * h0.w;
            acc.x += w1 * h1.x; acc.y += w1 * h1.y; acc.z += w1 * h1.z; acc.w += w1 * h1.w;
            acc.x += w2 * h2.x; acc.y += w2 * h2.y; acc.z += w2 * h2.z; acc.w += w2 * h2.w;
            acc.x += w3 * h3.x; acc.y += w3 * h3.y; acc.z += w3 * h3.z; acc.w += w3 * h3.w;
        }
        for (; e < e1; e++) {
            int2 c = csr[e];
            float w = __int_as_float(c.y);
            float4 hv = ld4v(h + (size_t)c.x * COLS + lane * 4);
            acc.x += w * hv.x; acc.y += w * hv.y; acc.z += w * hv.z; acc.w += w * hv.w;
        }
        st4v(z + (size_t)row * COLS + lane * 4, acc);
    } else {
        float2 a = ld2v(h + (size_t)row * COLS + lane * 2);
        float sw = selfw[row];
        float2 acc = make_float2(a.x * sw, a.y * sw);
        int e = rowptr[row];
        const int e1 = rowptr[row + 1];
        for (; e + 8 <= e1; e += 8) {
            int2 cc[8];
#pragma unroll
            for (int j = 0; j < 8; j++) cc[j] = csr[e + j];
            float2 hv[8];
#pragma unroll
            for (int j = 0; j < 8; j++) hv[j] = ld2v(h + (size_t)cc[j].x * COLS + lane * 2);
#pragma unroll
            for (int j = 0; j < 8; j++) {
                float w = __int_as_float(cc[j].y);
                acc.x += w * hv[j].x; acc.y += w * hv[j].y;
            }
        }
        for (; e + 4 <= e1; e += 4) {
            int2 c0 = csr[e], c1 = csr[e + 1], c2 = csr[e + 2], c3 = csr[e + 3];
            float2 h0 = ld2v(h + (size_t)c0.x * COLS + lane * 2);
            float2 h1 = ld2v(h + (size_t)c1.x * COLS + lane * 2);
            float2 h2 = ld2v(h + (size_t)c2.x * COLS + lane * 2);
            float2 h3 = ld2v(h + (size_t)c3.x * COLS + lane * 2);
            float w0 = __int_as_float(c0.y), w1 = __int_as_float(c1.y);
            float w2 = __int_as_float(c2.y), w3 = __int_as_float(c3.y);
            acc.x += w0 * h0.x; acc.y += w0 * h0.y;
            acc.x += w1 * h1.x; acc.y += w1 * h1.y;
            acc.x += w2 * h2.x; acc.y += w2 * h2.y;
            acc.x += w3 * h3.x; acc.y += w3 * h3.y;
        }
        for (; e < e1; e++) {
            int2 c = csr[e];
            float w = __int_as_float(c.y);
            float2 hv = ld2v(h + (size_t)c.x * COLS + lane * 2);
            acc.x += w * hv.x; acc.y += w * hv.y;
        }
        st2v(z + (size_t)row * COLS + lane * 2, acc);
    }
}

// ---------------- MFMA bf16 GEMM, persistent streaming structure ----------------
// grid = (256, 2): one resident round at 2 blocks/CU (launch_bounds caps VGPR at 128,
// LDS 2x65.5KB < 160KB). Block stages its B-half (128 cols x K) into LDS ONCE, then
// loops its 391-row range in two barrier-free iterations (8 waves x 32 rows each).
// Swapped-operand MFMA: acc regs = 4 consecutive C-cols of one row -> packed 8B stores.
// MODE 0: C = A@B + bias, fused per-column BN sums. MODE 1: relu-residual epilogue.

#define RPB 391   // rows per block: 256 * 391 >= NN

template<int K, int MODE>
__global__ __launch_bounds__(512, 4) void mgemm_k(const unsigned short* __restrict__ A,
                                                  const unsigned short* __restrict__ Bt,
                                                  const float* __restrict__ bias,
                                                  unsigned short* __restrict__ C,
                                                  const float* __restrict__ scale,
                                                  const float* __restrict__ shift,
                                                  const unsigned short* __restrict__ aggin,
                                                  float* __restrict__ sums, int M) {
    constexpr int NCOLS = 128;
    constexpr int NF = NCOLS / 16;            // 8 col-tiles per wave
    constexpr int SEGS = K / 8;               // 16B segments per B column
    constexpr int KS = K / 32;                // MFMA k-steps
    __shared__ char Bl[NCOLS * K * 2];        // swizzled [col][K]
    __shared__ float sstat[2 * NCOLS];
    const int tid  = threadIdx.x;
    const int lane = tid & 63;
    const int wid  = tid >> 6;                // 0..7
    const int q    = lane >> 4;               // 0..3  (k-quarter / col-quarter)
    const int rl   = lane & 15;               // row-within-16
    const int col0 = blockIdx.y * NCOLS;
    const int rbase = blockIdx.x * RPB;
    const int rend  = min(rbase + RPB, M);

    // ---- stage B-half into LDS (swizzled 16B segs), once per block ----
    for (int s = tid; s < NCOLS * SEGS; s += 512) {
        int col = s / SEGS, j = s % SEGS;
        uint4 v = *reinterpret_cast<const uint4*>(Bt + (size_t)(col0 + col) * K + j * 8);
        *reinterpret_cast<uint4*>(Bl + col * (K * 2) + (((j) ^ (col & 7)) << 4)) = v;
    }
    if (MODE == 0 && tid < 2 * NCOLS) sstat[tid] = 0.f;
    __syncthreads();

    for (int it = 0; it < 2; it++) {
        const int row0 = rbase + it * 256 + wid * 32;
        if (row0 >= rend) continue;            // wave-uniform; no barriers inside

        const int a0r = min(row0 + rl, M - 1);
        const int a1r = min(row0 + 16 + rl, M - 1);
        const unsigned short* pa0 = A + (size_t)a0r * K + q * 8;
        const unsigned short* pa1 = A + (size_t)a1r * K + q * 8;

        f32x4 acc[2][NF];
#pragma unroll
        for (int m = 0; m < 2; m++)
#pragma unroll
            for (int n = 0; n < NF; n++) acc[m][n] = (f32x4){0.f, 0.f, 0.f, 0.f};

#pragma unroll
        for (int ks = 0; ks < KS; ks++) {
            bf16x8 af0 = *reinterpret_cast<const bf16x8*>(pa0 + ks * 32);
            bf16x8 af1 = *reinterpret_cast<const bf16x8*>(pa1 + ks * 32);
#pragma unroll
            for (int nf = 0; nf < NF; nf++) {
                int col = nf * 16 + rl;
                bf16x8 bf = *reinterpret_cast<const bf16x8*>(Bl + col * (K * 2) + (((ks * 4 + q) ^ (col & 7)) << 4));
                acc[0][nf] = __builtin_amdgcn_mfma_f32_16x16x32_bf16(bf, af0, acc[0][nf], 0, 0, 0);
                acc[1][nf] = __builtin_amdgcn_mfma_f32_16x16x32_bf16(bf, af1, acc[1][nf], 0, 0, 0);
            }
        }

        // ---- epilogue: per-lane rows row0+rl / row0+16+rl, cols cb..cb+3 ----
        const int g0 = row0 + rl, g1 = row0 + 16 + rl;
        const bool ok0 = g0 < rend, ok1 = g1 < rend;
#pragma unroll
        for (int nf = 0; nf < NF; nf++) {
            int cb = col0 + nf * 16 + q * 4;
            f32x4 v0 = acc[0][nf], v1 = acc[1][nf];
            if (MODE == 0) {
                float4 bb = *reinterpret_cast<const float4*>(bias + cb);
                v0[0] += bb.x; v0[1] += bb.y; v0[2] += bb.z; v0[3] += bb.w;
                v1[0] += bb.x; v1[1] += bb.y; v1[2] += bb.z; v1[3] += bb.w;
            } else {
                float4 sc = *reinterpret_cast<const float4*>(scale + cb);
                float4 sh = *reinterpret_cast<const float4*>(shift + cb);
                if (ok0) {
                    ushort4 ag = *reinterpret_cast<const ushort4*>(aggin + (size_t)g0 * HD + cb);
                    v0[0] += fmaxf(fmaf(b2f(ag.x), sc.x, sh.x), 0.f);
                    v0[1] += fmaxf(fmaf(b2f(ag.y), sc.y, sh.y), 0.f);
                    v0[2] += fmaxf(fmaf(b2f(ag.z), sc.z, sh.z), 0.f);
                    v0[3] += fmaxf(fmaf(b2f(ag.w), sc.w, sh.w), 0.f);
                }
                if (ok1) {
                    ushort4 ag = *reinterpret_cast<const ushort4*>(aggin + (size_t)g1 * HD + cb);
                    v1[0] += fmaxf(fmaf(b2f(ag.x), sc.x, sh.x), 0.f);
                    v1[1] += fmaxf(fmaf(b2f(ag.y), sc.y, sh.y), 0.f);
                    v1[2] += fmaxf(fmaf(b2f(ag.z), sc.z, sh.z), 0.f);
                    v1[3] += fmaxf(fmaf(b2f(ag.w), sc.w, sh.w), 0.f);
                }
            }
            if (ok0) {
                ushort4 u; u.x = f2b(v0[0]); u.y = f2b(v0[1]); u.z = f2b(v0[2]); u.w = f2b(v0[3]);
                *reinterpret_cast<ushort4*>(C + (size_t)g0 * HD + cb) = u;
            }
            if (ok1) {
                ushort4 u; u.x = f2b(v1[0]); u.y = f2b(v1[1]); u.z = f2b(v1[2]); u.w = f2b(v1[3]);
                *reinterpret_cast<ushort4*>(C + (size_t)g1 * HD + cb) = u;
            }
            if (MODE == 0) {
                if (!ok0) { v0[0] = v0[1] = v0[2] = v0[3] = 0.f; }
                if (!ok1) { v1[0] = v1[1] = v1[2] = v1[3] = 0.f; }
                float s[4], qq[4];
#pragma unroll
                for (int j = 0; j < 4; j++) {
                    s[j]  = v0[j] + v1[j];
                    qq[j] = v0[j] * v0[j] + v1[j] * v1[j];
                }
#pragma unroll
                for (int m = 1; m < 16; m <<= 1) {
#pragma unroll
                    for (int j = 0; j < 4; j++) {
                        s[j]  += __shfl_xor(s[j], m, 64);
                        qq[j] += __shfl_xor(qq[j], m, 64);
                    }
                }
                if (rl == 0) {
                    int cl = nf * 16 + q * 4;
#pragma unroll
                    for (int j = 0; j < 4; j++) {
                        atomicAdd(&sstat[cl + j], s[j]);
                        atomicAdd(&sstat[NCOLS + cl + j], qq[j]);
                    }
                }
            }
        }
    }

    if (MODE == 0) {
        __syncthreads();
        if (tid < NCOLS)            atomicAdd(&sums[col0 + tid], sstat[tid]);
        else if (tid < 2 * NCOLS)   atomicAdd(&sums[HD + col0 + (tid - NCOLS)], sstat[tid]);
    }
}

// ---------------- BatchNorm finalize + epilogue ----------------

__global__ void bn_fin_k(const float* __restrict__ sums, const float* __restrict__ g,
                         const float* __restrict__ be, float* __restrict__ sc, float* __restrict__ sh) {
    int c = threadIdx.x;
    float m = sums[c] * (1.0f / NN);
    float v = sums[HD + c] * (1.0f / NN) - m * m;
    float s = g[c] * rsqrtf(v + BNEPS);
    sc[c] = s;
    sh[c] = be[c] - m * s;
}

__global__ __launch_bounds__(256) void epi_k(const unsigned short* __restrict__ agg,
                                             const unsigned short* __restrict__ res,
                                             const float* __restrict__ scp, const float* __restrict__ shp,
                                             unsigned short* __restrict__ out) {
    const size_t total = (size_t)NN * (HD / 4);
    size_t i = (size_t)blockIdx.x * 256 + threadIdx.x;
    const size_t stride = (size_t)gridDim.x * 256;
    for (; i < total; i += stride) {
        int cq = ((int)(i & 63)) * 4;
        float4 a = ld4v(agg + i * 4);
        float4 r = ld4v(res + i * 4);
        float4 sc = *reinterpret_cast<const float4*>(scp + cq);
        float4 sh = *reinterpret_cast<const float4*>(shp + cq);
        float4 o;
        o.x = fmaxf(fmaf(a.x, sc.x, sh.x), 0.f) + r.x;
        o.y = fmaxf(fmaf(a.y, sc.y, sh.y), 0.f) + r.y;
        o.z = fmaxf(fmaf(a.z, sc.z, sh.z), 0.f) + r.z;
        o.w = fmaxf(fmaf(a.w, sc.w, sh.w), 0.f) + r.w;
        st4v(out + i * 4, o);
    }
}

// ---------------- block-4 fused epilogue + pool (h4 never materialized) ----------------

__global__ __launch_bounds__(256) void epi_pool_k(const unsigned short* __restrict__ lin,
                                                  const unsigned short* __restrict__ res,
                                                  const float* __restrict__ scp, const float* __restrict__ shp,
                                                  const int* __restrict__ batch,
                                                  float* __restrict__ pooled) {
    const int c = threadIdx.x;
    const int rs = blockIdx.x * 250;
    if (rs >= NN) return;
    const int re = min(rs + 250, NN);
    const float sc = scp[c], sh = shp[c];
    float acc = 0.f;
    int cur = batch[rs];
    for (int r = rs; r < re; r++) {
        int g = batch[r];
        if (g != cur) { atomicAdd(&pooled[(size_t)cur * HD + c], acc); acc = 0.f; cur = g; }
        float a = b2f(lin[(size_t)r * HD + c]);
        float rr = b2f(res[(size_t)r * HD + c]);
        acc += fmaxf(fmaf(a, sc, sh), 0.f) + rr;
    }
    atomicAdd(&pooled[(size_t)cur * HD + c], acc);
}

__global__ void pool_out_k(const float* __restrict__ pooled, const int* __restrict__ batch,
                           const float* __restrict__ Wl, const float* __restrict__ bl,
                           float* __restrict__ out) {
    int g = threadIdx.x;
    if (g < NG) {
        auto lb = [&](int val) {
            int lo = 0, hi = NN;
            while (lo < hi) { int mid = (lo + hi) >> 1; if (batch[mid] < val) lo = mid + 1; else hi = mid; }
            return lo;
        };
        int c0 = lb(g), c1 = lb(g + 1);
        float cn = fmaxf((float)(c1 - c0), 1.0f);
        float s = 0.f;
        for (int c = 0; c < HD; c++) s += pooled[(size_t)g * HD + c] * Wl[c];
        out[g] = s / cn + bl[0];
    }
}

// ---------------- launcher ----------------

static inline size_t alignup(size_t x) { return (x + 255) & ~size_t(255); }

extern "C" void kernel_launch(void* const* d_in, const int* in_sizes, int n_in,
                              void* d_out, int out_size, void* d_ws, size_t ws_size,
                              hipStream_t stream) {
    const float* x    = (const float*)d_in[0];
    const int*   ei   = (const int*)d_in[1];
    const int*   bat  = (const int*)d_in[2];
    const float* W1   = (const float*)d_in[3];
    const float* bi1  = (const float*)d_in[4];
    const float* g1   = (const float*)d_in[5];
    const float* be1  = (const float*)d_in[6];
    const float* P1   = (const float*)d_in[7];
    const float* W2   = (const float*)d_in[8];
    const float* bi2  = (const float*)d_in[9];
    const float* g2   = (const float*)d_in[10];
    const float* be2  = (const float*)d_in[11];
    const float* W3   = (const float*)d_in[12];
    const float* bi3  = (const float*)d_in[13];
    const float* g3   = (const float*)d_in[14];
    const float* be3  = (const float*)d_in[15];
    const float* W4   = (const float*)d_in[16];
    const float* bi4  = (const float*)d_in[17];
    const float* g4   = (const float*)d_in[18];
    const float* be4  = (const float*)d_in[19];
    const float* Wl   = (const float*)d_in[20];
    const float* bl   = (const float*)d_in[21];
    float* out = (float*)d_out;

    const int* e_src = ei;
    const int* e_dst = ei + NE;

    typedef unsigned short ST;
    char* p = (char*)d_ws;
    auto alloc = [&](size_t bytes) { char* q = p; p += alignup(bytes); return q; };
    ST*    fb0     = (ST*)alloc((size_t)NN * HD * sizeof(ST));
    ST*    fb1     = (ST*)alloc((size_t)NN * HD * sizeof(ST));
    ST*    fb2     = (ST*)alloc((size_t)NN * HD * sizeof(ST));
    ST*    xb      = (ST*)alloc((size_t)NN * FIN * sizeof(ST));
    float* dis     = (float*)alloc((size_t)NN * 4);
    float* selfw   = (float*)alloc((size_t)NN * 4);
    int*   rowptr  = (int*)alloc((size_t)(NN + 1) * 4);
    int2*  csr     = (int2*)alloc((size_t)NE * 8);
    int*   partials= (int*)alloc(128 * 4);
    float* bnsc    = (float*)alloc(HD * 4);
    float* bnsh    = (float*)alloc(HD * 4);
    ST*    w1t     = (ST*)alloc(256 * 128 * sizeof(ST));
    ST*    p1t     = (ST*)alloc(256 * 128 * sizeof(ST));
    ST*    w2t     = (ST*)alloc(256 * 256 * sizeof(ST));
    ST*    w3t     = (ST*)alloc(256 * 256 * sizeof(ST));
    ST*    w4t     = (ST*)alloc(256 * 256 * sizeof(ST));
    // ---- single zeroed region: cnt | cursor | sums[4] | pooled ----
    size_t zbytes = (size_t)NN * 4 + (size_t)NN * 4 + 4 * 2 * HD * 4 + (size_t)NG * HD * 4;
    char*  zbase   = alloc(zbytes);
    int*   cnt     = (int*)zbase;
    int*   cursor  = (int*)(zbase + (size_t)NN * 4);
    float* sums1   = (float*)(zbase + (size_t)NN * 8);
    float* sums2   = sums1 + 2 * HD;
    float* sums3   = sums2 + 2 * HD;
    float* sums4   = sums3 + 2 * HD;
    float* pooled  = sums4 + 2 * HD;

    const int NB = (NN + 1023) / 1024;  // 98
    dim3 gg(256, 2);                    // persistent: one resident round at 2 blocks/CU

    hipMemsetAsync(zbase, 0, zbytes, stream);

    // ---- weight/x prep ----
    wt_all_k<<<1024, 256, 0, stream>>>(W1, P1, W2, W3, W4, w1t, p1t, w2t, w3t, w4t);
    x2b_k<<<(NN * FIN / 4 + 255) / 256, 256, 0, stream>>>(x, xb);

    // ---- graph preprocessing ----
    count_deg_k<<<(NE + 255) / 256, 256, 0, stream>>>(e_dst, cnt);
    node_prep_k<<<(NN + 255) / 256, 256, 0, stream>>>(cnt, dis, selfw);
    scan_reduce_k<<<NB, 1024, 0, stream>>>(cnt, partials);
    scan_partials_k<<<1, 64, 0, stream>>>(partials, NB);
    scan_write_k<<<NB, 1024, 0, stream>>>(cnt, partials, rowptr);
    fill_csr_k<<<(NE + 255) / 256, 256, 0, stream>>>(e_src, e_dst, rowptr, cursor, dis, csr);

    // ---- block 1 (x:128 -> 256, projection residual) ----
    spmm_k<128><<<NN / 4, 256, 0, stream>>>(xb, rowptr, csr, selfw, fb0);
    mgemm_k<128, 0><<<gg, 512, 0, stream>>>(fb0, w1t, bi1, fb2, nullptr, nullptr, nullptr, sums1, NN);
    bn_fin_k<<<1, 256, 0, stream>>>(sums1, g1, be1, bnsc, bnsh);
    mgemm_k<128, 1><<<gg, 512, 0, stream>>>(xb, p1t, nullptr, fb1, bnsc, bnsh, fb2, nullptr, NN);
    // h1 = fb1

    // ---- block 2 ----
    spmm_k<256><<<NN / 4, 256, 0, stream>>>(fb1, rowptr, csr, selfw, fb0);
    mgemm_k<256, 0><<<gg, 512, 0, stream>>>(fb0, w2t, bi2, fb2, nullptr, nullptr, nullptr, sums2, NN);
    bn_fin_k<<<1, 256, 0, stream>>>(sums2, g2, be2, bnsc, bnsh);
    epi_k<<<4096, 256, 0, stream>>>(fb2, fb1, bnsc, bnsh, fb0);
    // h2 = fb0

    // ---- block 3 ----
    spmm_k<256><<<NN / 4, 256, 0, stream>>>(fb0, rowptr, csr, selfw, fb1);
    mgemm_k<256, 0><<<gg, 512, 0, stream>>>(fb1, w3t, bi3, fb2, nullptr, nullptr, nullptr, sums3, NN);
    bn_fin_k<<<1, 256, 0, stream>>>(sums3, g3, be3, bnsc, bnsh);
    epi_k<<<4096, 256, 0, stream>>>(fb2, fb0, bnsc, bnsh, fb1);
    // h3 = fb1

    // ---- block 4 ----
    spmm_k<256><<<NN / 4, 256, 0, stream>>>(fb1, rowptr, csr, selfw, fb0);
    mgemm_k<256, 0><<<gg, 512, 0, stream>>>(fb0, w4t, bi4, fb2, nullptr, nullptr, nullptr, sums4, NN);
    bn_fin_k<<<1, 256, 0, stream>>>(sums4, g4, be4, bnsc, bnsh);
    // fused epilogue + pool: h4 never written to memory
    epi_pool_k<<<(NN + 249) / 250, 256, 0, stream>>>(fb2, fb1, bnsc, bnsh, bat, pooled);
    pool_out_k<<<1, 64, 0, stream>>>(pooled, bat, Wl, bl, out);
}

// Round 11
// 738.129 us; speedup vs baseline: 1.3910x; 1.0822x over previous
//
#include <hip/hip_runtime.h>
#include <cstdint>
#include <cstddef>

#define NN 100000
#define NE 1000000
#define FIN 128
#define HD 256
#define NG 64
#define BNEPS 1e-5f

typedef unsigned short ushort_t;
typedef __attribute__((ext_vector_type(8))) short bf16x8;
typedef __attribute__((ext_vector_type(4))) float f32x4;

// ---------- bf16<->f32 helpers (storage is raw bf16 bits in ushort) ----------

__device__ inline float b2f(unsigned short u) {
    union { float f; unsigned int i; } x; x.i = ((unsigned int)u) << 16; return x.f;
}
__device__ inline unsigned short f2b(float f) {
    union { float f; unsigned int i; } x; x.f = f;
    unsigned int r = x.i + 0x7FFFu + ((x.i >> 16) & 1u);
    return (unsigned short)(r >> 16);
}
__device__ inline float  ld1(const unsigned short* p) { return b2f(*p); }
__device__ inline float4 ld4v(const unsigned short* p) {
    ushort4 u = *(const ushort4*)p;
    return make_float4(b2f(u.x), b2f(u.y), b2f(u.z), b2f(u.w));
}
__device__ inline float2 ld2v(const unsigned short* p) {
    ushort2 u = *(const ushort2*)p;
    return make_float2(b2f(u.x), b2f(u.y));
}
__device__ inline void st4v(unsigned short* p, float4 v) {
    ushort4 u; u.x = f2b(v.x); u.y = f2b(v.y); u.z = f2b(v.z); u.w = f2b(v.w);
    *(ushort4*)p = u;
}
__device__ inline void st2v(unsigned short* p, float2 v) {
    ushort2 u; u.x = f2b(v.x); u.y = f2b(v.y);
    *(ushort2*)p = u;
}

// ---------------- graph preprocessing ----------------

__global__ __launch_bounds__(256) void count_deg_k(const int* __restrict__ dst, int* __restrict__ cnt) {
    int e = blockIdx.x * 256 + threadIdx.x;
    if (e < NE) atomicAdd(&cnt[dst[e]], 1);
}

__global__ __launch_bounds__(256) void node_prep_k(const int* __restrict__ cnt,
                                                   float* __restrict__ dis, float* __restrict__ selfw) {
    int i = blockIdx.x * 256 + threadIdx.x;
    if (i < NN) {
        float d = (float)cnt[i] + 1.0f;
        dis[i] = rsqrtf(d);
        selfw[i] = 1.0f / d;
    }
}

__global__ __launch_bounds__(1024) void scan_reduce_k(const int* __restrict__ cnt, int* __restrict__ partials) {
    __shared__ int sh[1024];
    int i = blockIdx.x * 1024 + threadIdx.x;
    sh[threadIdx.x] = (i < NN) ? cnt[i] : 0;
    __syncthreads();
    for (int off = 512; off > 0; off >>= 1) {
        if (threadIdx.x < off) sh[threadIdx.x] += sh[threadIdx.x + off];
        __syncthreads();
    }
    if (threadIdx.x == 0) partials[blockIdx.x] = sh[0];
}

__global__ void scan_partials_k(int* partials, int nb) {
    if (threadIdx.x == 0 && blockIdx.x == 0) {
        int run = 0;
        for (int b = 0; b < nb; b++) { int v = partials[b]; partials[b] = run; run += v; }
    }
}

__global__ __launch_bounds__(1024) void scan_write_k(const int* __restrict__ cnt,
                                                     const int* __restrict__ partials,
                                                     int* __restrict__ rowptr) {
    __shared__ int sh[1024];
    int i = blockIdx.x * 1024 + threadIdx.x;
    int v = (i < NN) ? cnt[i] : 0;
    sh[threadIdx.x] = v;
    __syncthreads();
    for (int off = 1; off < 1024; off <<= 1) {
        int t = (threadIdx.x >= off) ? sh[threadIdx.x - off] : 0;
        __syncthreads();
        sh[threadIdx.x] += t;
        __syncthreads();
    }
    if (i < NN) rowptr[i] = partials[blockIdx.x] + sh[threadIdx.x] - v;
    if (i == NN - 1) rowptr[NN] = partials[blockIdx.x] + sh[threadIdx.x];
}

// CSR packed as int2 {src, weight_bits}: one 8B load per edge in the SpMM.
__global__ __launch_bounds__(256) void fill_csr_k(const int* __restrict__ src, const int* __restrict__ dst,
                                                  const int* __restrict__ rowptr, int* __restrict__ cursor,
                                                  const float* __restrict__ dis,
                                                  int2* __restrict__ csr) {
    int e = blockIdx.x * 256 + threadIdx.x;
    if (e < NE) {
        int d = dst[e], s = src[e];
        int pos = rowptr[d] + atomicAdd(&cursor[d], 1);
        float w = dis[s] * dis[d];
        csr[pos] = make_int2(s, __float_as_int(w));
    }
}

// ---- x (fp32 [N,128]) -> bf16 ----
__global__ __launch_bounds__(256) void x2b_k(const float* __restrict__ x, unsigned short* __restrict__ xb) {
    int i = blockIdx.x * 256 + threadIdx.x;
    if (i < NN * FIN / 4) {
        float4 v = *reinterpret_cast<const float4*>(x + (size_t)i * 4);
        ushort4 u; u.x = f2b(v.x); u.y = f2b(v.y); u.z = f2b(v.z); u.w = f2b(v.w);
        *reinterpret_cast<ushort4*>(xb + (size_t)i * 4) = u;
    }
}

// ---- weight prep, all 5 in one launch: W[K][256] fp32 -> Bt[256][K] bf16 ----
__global__ __launch_bounds__(256) void wt_all_k(const float* __restrict__ W1, const float* __restrict__ P1,
                                                const float* __restrict__ W2, const float* __restrict__ W3,
                                                const float* __restrict__ W4,
                                                unsigned short* __restrict__ w1t, unsigned short* __restrict__ p1t,
                                                unsigned short* __restrict__ w2t, unsigned short* __restrict__ w3t,
                                                unsigned short* __restrict__ w4t) {
    int b = blockIdx.x;
    const float* W; unsigned short* Bt; int K; int base;
    if (b < 128)      { W = W1; Bt = w1t; K = 128; base = b; }
    else if (b < 256) { W = P1; Bt = p1t; K = 128; base = b - 128; }
    else if (b < 512) { W = W2; Bt = w2t; K = 256; base = b - 256; }
    else if (b < 768) { W = W3; Bt = w3t; K = 256; base = b - 512; }
    else              { W = W4; Bt = w4t; K = 256; base = b - 768; }
    int i = base * 256 + threadIdx.x;
    if (i < K * 256) {
        int k = i >> 8, n = i & 255;
        Bt[n * K + k] = f2b(W[k * 256 + n]);
    }
}

// ---------------- SpMM: z[i,:] = selfw[i]*h[i,:] + sum_e w_e * h[src_e,:] ----------------

template<int COLS>
__global__ __launch_bounds__(256) void spmm_k(const unsigned short* __restrict__ h,
                                              const int* __restrict__ rowptr,
                                              const int2* __restrict__ csr,
                                              const float* __restrict__ selfw,
                                              unsigned short* __restrict__ z) {
    const int lane = threadIdx.x & 63;
    const int row = blockIdx.x * 4 + (threadIdx.x >> 6);
    if (row >= NN) return;
    if constexpr (COLS == 256) {
        float4 a = ld4v(h + (size_t)row * COLS + lane * 4);
        float sw = selfw[row];
        float4 acc = make_float4(a.x * sw, a.y * sw, a.z * sw, a.w * sw);
        int e = rowptr[row];
        const int e1 = rowptr[row + 1];
        for (; e + 8 <= e1; e += 8) {
            int2 cc[8];
#pragma unroll
            for (int j = 0; j < 8; j++) cc[j] = csr[e + j];
            float4 hv[8];
#pragma unroll
            for (int j = 0; j < 8; j++) hv[j] = ld4v(h + (size_t)cc[j].x * COLS + lane * 4);
#pragma unroll
            for (int j = 0; j < 8; j++) {
                float w = __int_as_float(cc[j].y);
                acc.x += w * hv[j].x; acc.y += w * hv[j].y; acc.z += w * hv[j].z; acc.w += w * hv[j].w;
            }
        }
        for (; e + 4 <= e1; e += 4) {
            int2 c0 = csr[e], c1 = csr[e + 1], c2 = csr[e + 2], c3 = csr[e + 3];
            float4 h0 = ld4v(h + (size_t)c0.x * COLS + lane * 4);
            float4 h1 = ld4v(h + (size_t)c1.x * COLS + lane * 4);
            float4 h2 = ld4v(h + (size_t)c2.x * COLS + lane * 4);
            float4 h3 = ld4v(h + (size_t)c3.x * COLS + lane * 4);
            float w0 = __int_as_float(c0.y), w1 = __int_as_float(c1.y);
            float w2 = __int_as_float(c2.y), w3 = __int_as_float(c3.y);
            acc.x += w0 * h0.x; acc.y += w0 * h0.y; acc.z += w0 * h0.z; acc.w += w0 * h0.w;
            acc.x += w1 * h1.x; acc.y += w1 * h1.y; acc.z += w1 * h1.z; acc.w += w1 * h1.w;
            acc.x += w2 * h2.x; acc.y += w2 * h2.y; acc.z += w2 * h2.z; acc.w += w2 * h2.w;
            acc.x += w3 * h3.x; acc.y += w3 * h3.y; acc.z += w3 * h3.z; acc.w += w3 * h3.w;
        }
        for (; e < e1; e++) {
            int2 c = csr[e];
            float w = __int_as_float(c.y);
            float4 hv = ld4v(h + (size_t)c.x * COLS + lane * 4);
            acc.x += w * hv.x; acc.y += w * hv.y; acc.z += w * hv.z; acc.w += w * hv.w;
        }
        st4v(z + (size_t)row * COLS + lane * 4, acc);
    } else {
        float2 a = ld2v(h + (size_t)row * COLS + lane * 2);
        float sw = selfw[row];
        float2 acc = make_float2(a.x * sw, a.y * sw);
        int e = rowptr[row];
        const int e1 = rowptr[row + 1];
        for (; e + 8 <= e1; e += 8) {
            int2 cc[8];
#pragma unroll
            for (int j = 0; j < 8; j++) cc[j] = csr[e + j];
            float2 hv[8];
#pragma unroll
            for (int j = 0; j < 8; j++) hv[j] = ld2v(h + (size_t)cc[j].x * COLS + lane * 2);
#pragma unroll
            for (int j = 0; j < 8; j++) {
                float w = __int_as_float(cc[j].y);
                acc.x += w * hv[j].x; acc.y += w * hv[j].y;
            }
        }
        for (; e + 4 <= e1; e += 4) {
            int2 c0 = csr[e], c1 = csr[e + 1], c2 = csr[e + 2], c3 = csr[e + 3];
            float2 h0 = ld2v(h + (size_t)c0.x * COLS + lane * 2);
            float2 h1 = ld2v(h + (size_t)c1.x * COLS + lane * 2);
            float2 h2 = ld2v(h + (size_t)c2.x * COLS + lane * 2);
            float2 h3 = ld2v(h + (size_t)c3.x * COLS + lane * 2);
            float w0 = __int_as_float(c0.y), w1 = __int_as_float(c1.y);
            float w2 = __int_as_float(c2.y), w3 = __int_as_float(c3.y);
            acc.x += w0 * h0.x; acc.y += w0 * h0.y;
            acc.x += w1 * h1.x; acc.y += w1 * h1.y;
            acc.x += w2 * h2.x; acc.y += w2 * h2.y;
            acc.x += w3 * h3.x; acc.y += w3 * h3.y;
        }
        for (; e < e1; e++) {
            int2 c = csr[e];
            float w = __int_as_float(c.y);
            float2 hv = ld2v(h + (size_t)c.x * COLS + lane * 2);
            acc.x += w * hv.x; acc.y += w * hv.y;
        }
        st2v(z + (size_t)row * COLS + lane * 2, acc);
    }
}

// ---------------- MFMA bf16 GEMM, persistent streaming structure ----------------
// grid = (256, 2): one resident round at 2 blocks/CU. Block stages its B-half into LDS
// ONCE, then loops its 391-row range in two barrier-free iterations (8 waves x 32 rows).
// Swapped-operand MFMA: acc regs = 4 consecutive C-cols of one row -> packed 8B stores.
// MODE 0: C = A@B + bias, fused per-column BN sums. MODE 1: relu-residual epilogue.

#define RPB 391   // rows per block: 256 * 391 >= NN

template<int K, int MODE>
__global__ __launch_bounds__(512, 4) void mgemm_k(const unsigned short* __restrict__ A,
                                                  const unsigned short* __restrict__ Bt,
                                                  const float* __restrict__ bias,
                                                  unsigned short* __restrict__ C,
                                                  const float* __restrict__ scale,
                                                  const float* __restrict__ shift,
                                                  const unsigned short* __restrict__ aggin,
                                                  float* __restrict__ sums, int M) {
    constexpr int NCOLS = 128;
    constexpr int NF = NCOLS / 16;            // 8 col-tiles per wave
    constexpr int SEGS = K / 8;               // 16B segments per B column
    constexpr int KS = K / 32;                // MFMA k-steps
    __shared__ char Bl[NCOLS * K * 2];        // swizzled [col][K]
    __shared__ float sstat[2 * NCOLS];
    const int tid  = threadIdx.x;
    const int lane = tid & 63;
    const int wid  = tid >> 6;                // 0..7
    const int q    = lane >> 4;               // 0..3  (k-quarter / col-quarter)
    const int rl   = lane & 15;               // row-within-16
    const int col0 = blockIdx.y * NCOLS;
    const int rbase = blockIdx.x * RPB;
    const int rend  = min(rbase + RPB, M);

    // ---- stage B-half into LDS (swizzled 16B segs), once per block ----
    for (int s = tid; s < NCOLS * SEGS; s += 512) {
        int col = s / SEGS, j = s % SEGS;
        uint4 v = *reinterpret_cast<const uint4*>(Bt + (size_t)(col0 + col) * K + j * 8);
        *reinterpret_cast<uint4*>(Bl + col * (K * 2) + (((j) ^ (col & 7)) << 4)) = v;
    }
    if (MODE == 0 && tid < 2 * NCOLS) sstat[tid] = 0.f;
    __syncthreads();

    for (int it = 0; it < 2; it++) {
        const int row0 = rbase + it * 256 + wid * 32;
        if (row0 >= rend) continue;            // wave-uniform; no barriers inside

        const int a0r = min(row0 + rl, M - 1);
        const int a1r = min(row0 + 16 + rl, M - 1);
        const unsigned short* pa0 = A + (size_t)a0r * K + q * 8;
        const unsigned short* pa1 = A + (size_t)a1r * K + q * 8;

        f32x4 acc[2][NF];
#pragma unroll
        for (int m = 0; m < 2; m++)
#pragma unroll
            for (int n = 0; n < NF; n++) acc[m][n] = (f32x4){0.f, 0.f, 0.f, 0.f};

#pragma unroll
        for (int ks = 0; ks < KS; ks++) {
            bf16x8 af0 = *reinterpret_cast<const bf16x8*>(pa0 + ks * 32);
            bf16x8 af1 = *reinterpret_cast<const bf16x8*>(pa1 + ks * 32);
#pragma unroll
            for (int nf = 0; nf < NF; nf++) {
                int col = nf * 16 + rl;
                bf16x8 bf = *reinterpret_cast<const bf16x8*>(Bl + col * (K * 2) + (((ks * 4 + q) ^ (col & 7)) << 4));
                acc[0][nf] = __builtin_amdgcn_mfma_f32_16x16x32_bf16(bf, af0, acc[0][nf], 0, 0, 0);
                acc[1][nf] = __builtin_amdgcn_mfma_f32_16x16x32_bf16(bf, af1, acc[1][nf], 0, 0, 0);
            }
        }

        // ---- epilogue: per-lane rows row0+rl / row0+16+rl, cols cb..cb+3 ----
        const int g0 = row0 + rl, g1 = row0 + 16 + rl;
        const bool ok0 = g0 < rend, ok1 = g1 < rend;
#pragma unroll
        for (int nf = 0; nf < NF; nf++) {
            int cb = col0 + nf * 16 + q * 4;
            f32x4 v0 = acc[0][nf], v1 = acc[1][nf];
            if (MODE == 0) {
                float4 bb = *reinterpret_cast<const float4*>(bias + cb);
                v0[0] += bb.x; v0[1] += bb.y; v0[2] += bb.z; v0[3] += bb.w;
                v1[0] += bb.x; v1[1] += bb.y; v1[2] += bb.z; v1[3] += bb.w;
            } else {
                float4 sc = *reinterpret_cast<const float4*>(scale + cb);
                float4 sh = *reinterpret_cast<const float4*>(shift + cb);
                if (ok0) {
                    ushort4 ag = *reinterpret_cast<const ushort4*>(aggin + (size_t)g0 * HD + cb);
                    v0[0] += fmaxf(fmaf(b2f(ag.x), sc.x, sh.x), 0.f);
                    v0[1] += fmaxf(fmaf(b2f(ag.y), sc.y, sh.y), 0.f);
                    v0[2] += fmaxf(fmaf(b2f(ag.z), sc.z, sh.z), 0.f);
                    v0[3] += fmaxf(fmaf(b2f(ag.w), sc.w, sh.w), 0.f);
                }
                if (ok1) {
                    ushort4 ag = *reinterpret_cast<const ushort4*>(aggin + (size_t)g1 * HD + cb);
                    v1[0] += fmaxf(fmaf(b2f(ag.x), sc.x, sh.x), 0.f);
                    v1[1] += fmaxf(fmaf(b2f(ag.y), sc.y, sh.y), 0.f);
                    v1[2] += fmaxf(fmaf(b2f(ag.z), sc.z, sh.z), 0.f);
                    v1[3] += fmaxf(fmaf(b2f(ag.w), sc.w, sh.w), 0.f);
                }
            }
            if (ok0) {
                ushort4 u; u.x = f2b(v0[0]); u.y = f2b(v0[1]); u.z = f2b(v0[2]); u.w = f2b(v0[3]);
                *reinterpret_cast<ushort4*>(C + (size_t)g0 * HD + cb) = u;
            }
            if (ok1) {
                ushort4 u; u.x = f2b(v1[0]); u.y = f2b(v1[1]); u.z = f2b(v1[2]); u.w = f2b(v1[3]);
                *reinterpret_cast<ushort4*>(C + (size_t)g1 * HD + cb) = u;
            }
            if (MODE == 0) {
                if (!ok0) { v0[0] = v0[1] = v0[2] = v0[3] = 0.f; }
                if (!ok1) { v1[0] = v1[1] = v1[2] = v1[3] = 0.f; }
                float s[4], qq[4];
#pragma unroll
                for (int j = 0; j < 4; j++) {
                    s[j]  = v0[j] + v1[j];
                    qq[j] = v0[j] * v0[j] + v1[j] * v1[j];
                }
#pragma unroll
                for (int m = 1; m < 16; m <<= 1) {
#pragma unroll
                    for (int j = 0; j < 4; j++) {
                        s[j]  += __shfl_xor(s[j], m, 64);
                        qq[j] += __shfl_xor(qq[j], m, 64);
                    }
                }
                if (rl == 0) {
                    int cl = nf * 16 + q * 4;
#pragma unroll
                    for (int j = 0; j < 4; j++) {
                        atomicAdd(&sstat[cl + j], s[j]);
                        atomicAdd(&sstat[NCOLS + cl + j], qq[j]);
                    }
                }
            }
        }
    }

    if (MODE == 0) {
        __syncthreads();
        if (tid < NCOLS)            atomicAdd(&sums[col0 + tid], sstat[tid]);
        else if (tid < 2 * NCOLS)   atomicAdd(&sums[HD + col0 + (tid - NCOLS)], sstat[tid]);
    }
}

// ---------------- BatchNorm finalize + epilogue ----------------

__global__ void bn_fin_k(const float* __restrict__ sums, const float* __restrict__ g,
                         const float* __restrict__ be, float* __restrict__ sc, float* __restrict__ sh) {
    int c = threadIdx.x;
    float m = sums[c] * (1.0f / NN);
    float v = sums[HD + c] * (1.0f / NN) - m * m;
    float s = g[c] * rsqrtf(v + BNEPS);
    sc[c] = s;
    sh[c] = be[c] - m * s;
}

__global__ __launch_bounds__(256) void epi_k(const unsigned short* __restrict__ agg,
                                             const unsigned short* __restrict__ res,
                                             const float* __restrict__ scp, const float* __restrict__ shp,
                                             unsigned short* __restrict__ out) {
    const size_t total = (size_t)NN * (HD / 4);
    size_t i = (size_t)blockIdx.x * 256 + threadIdx.x;
    const size_t stride = (size_t)gridDim.x * 256;
    for (; i < total; i += stride) {
        int cq = ((int)(i & 63)) * 4;
        float4 a = ld4v(agg + i * 4);
        float4 r = ld4v(res + i * 4);
        float4 sc = *reinterpret_cast<const float4*>(scp + cq);
        float4 sh = *reinterpret_cast<const float4*>(shp + cq);
        float4 o;
        o.x = fmaxf(fmaf(a.x, sc.x, sh.x), 0.f) + r.x;
        o.y = fmaxf(fmaf(a.y, sc.y, sh.y), 0.f) + r.y;
        o.z = fmaxf(fmaf(a.z, sc.z, sh.z), 0.f) + r.z;
        o.w = fmaxf(fmaf(a.w, sc.w, sh.w), 0.f) + r.w;
        st4v(out + i * 4, o);
    }
}

// ---------------- block-4 fused epilogue + pool (h4 never materialized) ----------------
// 40 rows/block (2500 blocks ~ 10/CU) + x4 row unroll with all loads issued before the
// group-boundary logic -> 8 outstanding loads/wave (breaks the 1-row serial latency chain).

#define EP_RPB 40

__global__ __launch_bounds__(256) void epi_pool_k(const unsigned short* __restrict__ lin,
                                                  const unsigned short* __restrict__ res,
                                                  const float* __restrict__ scp, const float* __restrict__ shp,
                                                  const int* __restrict__ batch,
                                                  float* __restrict__ pooled) {
    const int c = threadIdx.x;
    const int rs = blockIdx.x * EP_RPB;
    if (rs >= NN) return;
    const int re = min(rs + EP_RPB, NN);
    const float sc = scp[c], sh = shp[c];
    float acc = 0.f;
    int cur = batch[rs];
    int r = rs;
    for (; r + 4 <= re; r += 4) {
        float a[4], rr[4]; int g[4];
#pragma unroll
        for (int j = 0; j < 4; j++) {
            a[j]  = b2f(lin[(size_t)(r + j) * HD + c]);
            rr[j] = b2f(res[(size_t)(r + j) * HD + c]);
            g[j]  = batch[r + j];
        }
#pragma unroll
        for (int j = 0; j < 4; j++) {
            if (g[j] != cur) { atomicAdd(&pooled[(size_t)cur * HD + c], acc); acc = 0.f; cur = g[j]; }
            acc += fmaxf(fmaf(a[j], sc, sh), 0.f) + rr[j];
        }
    }
    for (; r < re; r++) {
        int g = batch[r];
        if (g != cur) { atomicAdd(&pooled[(size_t)cur * HD + c], acc); acc = 0.f; cur = g; }
        float a = b2f(lin[(size_t)r * HD + c]);
        float rv = b2f(res[(size_t)r * HD + c]);
        acc += fmaxf(fmaf(a, sc, sh), 0.f) + rv;
    }
    atomicAdd(&pooled[(size_t)cur * HD + c], acc);
}

__global__ void pool_out_k(const float* __restrict__ pooled, const int* __restrict__ batch,
                           const float* __restrict__ Wl, const float* __restrict__ bl,
                           float* __restrict__ out) {
    int g = threadIdx.x;
    if (g < NG) {
        auto lb = [&](int val) {
            int lo = 0, hi = NN;
            while (lo < hi) { int mid = (lo + hi) >> 1; if (batch[mid] < val) lo = mid + 1; else hi = mid; }
            return lo;
        };
        int c0 = lb(g), c1 = lb(g + 1);
        float cn = fmaxf((float)(c1 - c0), 1.0f);
        float s = 0.f;
        for (int c = 0; c < HD; c++) s += pooled[(size_t)g * HD + c] * Wl[c];
        out[g] = s / cn + bl[0];
    }
}

// ---------------- launcher ----------------

static inline size_t alignup(size_t x) { return (x + 255) & ~size_t(255); }

extern "C" void kernel_launch(void* const* d_in, const int* in_sizes, int n_in,
                              void* d_out, int out_size, void* d_ws, size_t ws_size,
                              hipStream_t stream) {
    const float* x    = (const float*)d_in[0];
    const int*   ei   = (const int*)d_in[1];
    const int*   bat  = (const int*)d_in[2];
    const float* W1   = (const float*)d_in[3];
    const float* bi1  = (const float*)d_in[4];
    const float* g1   = (const float*)d_in[5];
    const float* be1  = (const float*)d_in[6];
    const float* P1   = (const float*)d_in[7];
    const float* W2   = (const float*)d_in[8];
    const float* bi2  = (const float*)d_in[9];
    const float* g2   = (const float*)d_in[10];
    const float* be2  = (const float*)d_in[11];
    const float* W3   = (const float*)d_in[12];
    const float* bi3  = (const float*)d_in[13];
    const float* g3   = (const float*)d_in[14];
    const float* be3  = (const float*)d_in[15];
    const float* W4   = (const float*)d_in[16];
    const float* bi4  = (const float*)d_in[17];
    const float* g4   = (const float*)d_in[18];
    const float* be4  = (const float*)d_in[19];
    const float* Wl   = (const float*)d_in[20];
    const float* bl   = (const float*)d_in[21];
    float* out = (float*)d_out;

    const int* e_src = ei;
    const int* e_dst = ei + NE;

    typedef unsigned short ST;
    char* p = (char*)d_ws;
    auto alloc = [&](size_t bytes) { char* q = p; p += alignup(bytes); return q; };
    ST*    fb0     = (ST*)alloc((size_t)NN * HD * sizeof(ST));
    ST*    fb1     = (ST*)alloc((size_t)NN * HD * sizeof(ST));
    ST*    fb2     = (ST*)alloc((size_t)NN * HD * sizeof(ST));
    ST*    xb      = (ST*)alloc((size_t)NN * FIN * sizeof(ST));
    float* dis     = (float*)alloc((size_t)NN * 4);
    float* selfw   = (float*)alloc((size_t)NN * 4);
    int*   rowptr  = (int*)alloc((size_t)(NN + 1) * 4);
    int2*  csr     = (int2*)alloc((size_t)NE * 8);
    int*   partials= (int*)alloc(128 * 4);
    float* bnsc    = (float*)alloc(HD * 4);
    float* bnsh    = (float*)alloc(HD * 4);
    ST*    w1t     = (ST*)alloc(256 * 128 * sizeof(ST));
    ST*    p1t     = (ST*)alloc(256 * 128 * sizeof(ST));
    ST*    w2t     = (ST*)alloc(256 * 256 * sizeof(ST));
    ST*    w3t     = (ST*)alloc(256 * 256 * sizeof(ST));
    ST*    w4t     = (ST*)alloc(256 * 256 * sizeof(ST));
    // ---- single zeroed region: cnt | cursor | sums[4] | pooled ----
    size_t zbytes = (size_t)NN * 4 + (size_t)NN * 4 + 4 * 2 * HD * 4 + (size_t)NG * HD * 4;
    char*  zbase   = alloc(zbytes);
    int*   cnt     = (int*)zbase;
    int*   cursor  = (int*)(zbase + (size_t)NN * 4);
    float* sums1   = (float*)(zbase + (size_t)NN * 8);
    float* sums2   = sums1 + 2 * HD;
    float* sums3   = sums2 + 2 * HD;
    float* sums4   = sums3 + 2 * HD;
    float* pooled  = sums4 + 2 * HD;

    const int NB = (NN + 1023) / 1024;  // 98
    dim3 gg(256, 2);                    // persistent: one resident round at 2 blocks/CU

    hipMemsetAsync(zbase, 0, zbytes, stream);

    // ---- weight/x prep ----
    wt_all_k<<<1024, 256, 0, stream>>>(W1, P1, W2, W3, W4, w1t, p1t, w2t, w3t, w4t);
    x2b_k<<<(NN * FIN / 4 + 255) / 256, 256, 0, stream>>>(x, xb);

    // ---- graph preprocessing ----
    count_deg_k<<<(NE + 255) / 256, 256, 0, stream>>>(e_dst, cnt);
    node_prep_k<<<(NN + 255) / 256, 256, 0, stream>>>(cnt, dis, selfw);
    scan_reduce_k<<<NB, 1024, 0, stream>>>(cnt, partials);
    scan_partials_k<<<1, 64, 0, stream>>>(partials, NB);
    scan_write_k<<<NB, 1024, 0, stream>>>(cnt, partials, rowptr);
    fill_csr_k<<<(NE + 255) / 256, 256, 0, stream>>>(e_src, e_dst, rowptr, cursor, dis, csr);

    // ---- block 1 (x:128 -> 256, projection residual) ----
    spmm_k<128><<<NN / 4, 256, 0, stream>>>(xb, rowptr, csr, selfw, fb0);
    mgemm_k<128, 0><<<gg, 512, 0, stream>>>(fb0, w1t, bi1, fb2, nullptr, nullptr, nullptr, sums1, NN);
    bn_fin_k<<<1, 256, 0, stream>>>(sums1, g1, be1, bnsc, bnsh);
    mgemm_k<128, 1><<<gg, 512, 0, stream>>>(xb, p1t, nullptr, fb1, bnsc, bnsh, fb2, nullptr, NN);
    // h1 = fb1

    // ---- block 2 ----
    spmm_k<256><<<NN / 4, 256, 0, stream>>>(fb1, rowptr, csr, selfw, fb0);
    mgemm_k<256, 0><<<gg, 512, 0, stream>>>(fb0, w2t, bi2, fb2, nullptr, nullptr, nullptr, sums2, NN);
    bn_fin_k<<<1, 256, 0, stream>>>(sums2, g2, be2, bnsc, bnsh);
    epi_k<<<4096, 256, 0, stream>>>(fb2, fb1, bnsc, bnsh, fb0);
    // h2 = fb0

    // ---- block 3 ----
    spmm_k<256><<<NN / 4, 256, 0, stream>>>(fb0, rowptr, csr, selfw, fb1);
    mgemm_k<256, 0><<<gg, 512, 0, stream>>>(fb1, w3t, bi3, fb2, nullptr, nullptr, nullptr, sums3, NN);
    bn_fin_k<<<1, 256, 0, stream>>>(sums3, g3, be3, bnsc, bnsh);
    epi_k<<<4096, 256, 0, stream>>>(fb2, fb0, bnsc, bnsh, fb1);
    // h3 = fb1

    // ---- block 4 ----
    spmm_k<256><<<NN / 4, 256, 0, stream>>>(fb1, rowptr, csr, selfw, fb0);
    mgemm_k<256, 0><<<gg, 512, 0, stream>>>(fb0, w4t, bi4, fb2, nullptr, nullptr, nullptr, sums4, NN);
    bn_fin_k<<<1, 256, 0, stream>>>(sums4, g4, be4, bnsc, bnsh);
    // fused epilogue + pool: h4 never written to memory
    epi_pool_k<<<(NN + EP_RPB - 1) / EP_RPB, 256, 0, stream>>>(fb2, fb1, bnsc, bnsh, bat, pooled);
    pool_out_k<<<1, 64, 0, stream>>>(pooled, bat, Wl, bl, out);
}